// Round 3
// baseline (4202.533 us; speedup 1.0000x reference)
//
#include <hip/hip_runtime.h>

static constexpr int gT = 256;   // time steps
static constexpr int gV = 24;    // graph nodes
static constexpr float BN_INV = 0.99999500003749969f; // 1/sqrt(1+1e-5)

// ============================= prep kernels =============================
__global__ __launch_bounds__(256) void k_prep_aeff(
    const float* __restrict__ A, const float* __restrict__ e0,
    const float* __restrict__ e1, const float* __restrict__ e2,
    float* __restrict__ aeff, float* __restrict__ csum)
{
  int tid = blockIdx.x * 256 + threadIdx.x;
  if (tid < 3 * 1728) {
    int l = tid / 1728, r = tid % 1728;
    const float* e = (l == 0) ? e0 : ((l == 1) ? e1 : e2);
    aeff[tid] = A[r] * e[r];
  }
  if (tid < 3 * 72) {
    int l = tid / 72, r = tid % 72;
    int k = r / 24, w = r % 24;
    const float* e = (l == 0) ? e0 : ((l == 1) ? e1 : e2);
    float s = 0.f;
    for (int v = 0; v < 24; ++v) { int idx = (k * 24 + v) * 24 + w; s += A[idx] * e[idx]; }
    csum[tid] = s;
  }
}

// out[(k*Cin+ci)*Cout + c] = in[(k*Cout+c)*Cin + ci]
__global__ __launch_bounds__(256) void k_transpose(
    const float* __restrict__ in, float* __restrict__ out, int K, int Cin, int Cout)
{
  int idx = blockIdx.x * 256 + threadIdx.x;
  int total = K * Cin * Cout;
  if (idx >= total) return;
  int kk = idx / Cout, c = idx % Cout;
  int k = kk / Cin, ci = kk % Cin;
  out[idx] = in[(size_t)(k * Cout + c) * Cin + ci];
}

// ============================= layer 0 GCN =============================
__global__ __launch_bounds__(256) void k_gcn0(
    const float* __restrict__ x,      // [B][T][24][3]
    const float* __restrict__ aeff,   // [3][24][24]
    const float* __restrict__ csum,   // [3][24]
    const float* __restrict__ dbg, const float* __restrict__ dbb,  // [72]
    const float* __restrict__ W0,     // [768][3]
    const float* __restrict__ gb0,    // [768]
    const float* __restrict__ g1, const float* __restrict__ b1,    // [256]
    float* __restrict__ y_out,        // [Bc][T][256][24]
    int b0)
{
  __shared__ float xbn[72];      // [cin][v]
  __shared__ float XA[216];      // [(k*3+ci)][w]
  __shared__ float WL[2304];
  __shared__ float tile[256 * 25];
  int t = blockIdx.x, bl = blockIdx.y, tid = threadIdx.x;
  int b = b0 + bl;

  if (tid < 72) {
    int v = tid / 3, cin = tid % 3;
    float xv = x[(((size_t)b * gT + t) * gV + v) * 3 + cin];
    xbn[cin * 24 + v] = xv * (BN_INV * dbg[tid]) + dbb[tid];
  }
  for (int i = tid; i < 2304; i += 256) WL[i] = W0[i];
  __syncthreads();

  if (tid < 216) {
    int k = tid / 72, r = tid % 72, ci = r / 24, w = r % 24;
    const float* Ak = aeff + k * 576;
    float s = 0.f;
#pragma unroll
    for (int v = 0; v < 24; ++v) s += xbn[ci * 24 + v] * Ak[v * 24 + w];
    XA[tid] = s;
  }
  __syncthreads();

  int c = tid;
  float acc[24];
#pragma unroll
  for (int w = 0; w < 24; ++w) acc[w] = 0.f;
#pragma unroll
  for (int k = 0; k < 3; ++k) {
#pragma unroll
    for (int ci = 0; ci < 3; ++ci) {
      float wv = WL[(k * 256 + c) * 3 + ci];
#pragma unroll
      for (int w = 0; w < 24; ++w) acc[w] += wv * XA[(k * 3 + ci) * 24 + w];
    }
    float gv = gb0[k * 256 + c];
#pragma unroll
    for (int w = 0; w < 24; ++w) acc[w] += gv * csum[k * 24 + w];
  }
  float s1 = BN_INV * g1[c], o1 = b1[c];
#pragma unroll
  for (int w = 0; w < 24; ++w) tile[c * 25 + w] = fmaxf(acc[w] * s1 + o1, 0.f);
  __syncthreads();

  float* ob = y_out + ((size_t)bl * gT + t) * 6144;
#pragma unroll
  for (int i = 0; i < 6; ++i) {
    int f4 = i * 256 + tid;
    int f = f4 * 4;
    float4 vv;
    vv.x = tile[((f + 0) / 24) * 25 + (f + 0) % 24];
    vv.y = tile[((f + 1) / 24) * 25 + (f + 1) % 24];
    vv.z = tile[((f + 2) / 24) * 25 + (f + 2) % 24];
    vv.w = tile[((f + 3) / 24) * 25 + (f + 3) % 24];
    ((float4*)ob)[f4] = vv;
  }
}

// ============================= layers 1,2 GCN + residual =============================
// W-first: per stream s in {k0,k1,k2,res}: Z_s[c,v] = sum_ci W_s[c,ci] h[ci,v]
// (split-K over S=256/COUT thread slices, reduced in LDS), then
// y[c,w] += sum_v Z_k[c,v] Aeff[k,v,w]  (res consumed directly).
template <int CIN, int COUT>
__global__ __launch_bounds__(256, 4) void k_gcn12(
    const float* __restrict__ h_in,   // [Bc][T][CIN][24]
    const float* __restrict__ aeffL,  // [3][24][24]
    const float* __restrict__ csumL,  // [3][24]
    const float* __restrict__ Wg,     // [(k*CIN+ci)][COUT]
    const float* __restrict__ gb,     // [3*COUT]
    const float* __restrict__ g1, const float* __restrict__ b1,
    const float* __restrict__ Wr,     // [ci][COUT]
    const float* __restrict__ rb, const float* __restrict__ rg, const float* __restrict__ rbb,
    float* __restrict__ y_out,        // [Bc][T][COUT][24]
    float* __restrict__ r_out)        // [Bc][T][COUT][24]
{
  constexpr int S = 256 / COUT;   // split-K ways (2 for 128, 4 for 64)
  constexpr int KS = CIN / S;     // ci per slice
  constexpr int WR = 24 / S;      // w per thread in contraction
  __shared__ float hL[CIN * 24];
  __shared__ float ZL[COUT * 25]; // stride 25: conflict-free lane-per-c access
  __shared__ float AL[3 * 576];
  __shared__ float csL[72];
  int t = blockIdx.x, bl = blockIdx.y, tid = threadIdx.x;
  int c = tid & (COUT - 1);
  int h = tid / COUT;             // slice id
  int w0 = h * WR;

  const float* hbase = h_in + ((size_t)bl * gT + t) * CIN * 24;
  for (int i = tid; i < CIN * 24 / 4; i += 256)
    ((float4*)hL)[i] = ((const float4*)hbase)[i];
  for (int i = tid; i < 3 * 576 / 4; i += 256)
    ((float4*)AL)[i] = ((const float4*)aeffL)[i];
  if (tid < 72) csL[tid] = csumL[tid];
  __syncthreads();

  float yac[WR];
#pragma unroll
  for (int j = 0; j < WR; ++j) yac[j] = 0.f;
  float rv[WR];

  for (int s = 0; s < 4; ++s) {
    const float* Wbase = (s < 3) ? (Wg + (size_t)s * CIN * COUT) : Wr;
    float part[24];
#pragma unroll
    for (int v = 0; v < 24; ++v) part[v] = 0.f;
    int ci0 = h * KS;
#pragma unroll 4
    for (int ci = ci0; ci < ci0 + KS; ++ci) {
      float wv = Wbase[(size_t)ci * COUT + c];
      const float* hp = &hL[ci * 24];
#pragma unroll
      for (int v = 0; v < 24; ++v) part[v] += wv * hp[v];
    }
    // serial slice-reduce into ZL
    for (int ss = 0; ss < S; ++ss) {
      if (h == ss) {
        if (ss == 0) {
#pragma unroll
          for (int v = 0; v < 24; ++v) ZL[c * 25 + v] = part[v];
        } else {
#pragma unroll
          for (int v = 0; v < 24; ++v) ZL[c * 25 + v] += part[v];
        }
      }
      __syncthreads();
    }
    if (s < 3) {
      const float* Ak = &AL[s * 576];
      for (int v = 0; v < 24; ++v) {
        float zv = ZL[c * 25 + v];
#pragma unroll
        for (int j = 0; j < WR; ++j) yac[j] += zv * Ak[v * 24 + w0 + j];
      }
    } else {
#pragma unroll
      for (int j = 0; j < WR; ++j) rv[j] = ZL[c * 25 + w0 + j];
    }
    __syncthreads();  // ZL reused by next stream
  }

  // epilogue: bias, BN, relu; stage into hL (done with it) for coalesced writes
  float* tY = hL;
  float* tR = hL + COUT * 24;
  float s1 = BN_INV * g1[c], o1 = b1[c];
  float sr = BN_INV * rg[c], orr = rbb[c], rbv = rb[c];
  float gv0 = gb[c], gv1 = gb[COUT + c], gv2 = gb[2 * COUT + c];
#pragma unroll
  for (int j = 0; j < WR; ++j) {
    float bias = gv0 * csL[w0 + j] + gv1 * csL[24 + w0 + j] + gv2 * csL[48 + w0 + j];
    tY[c * 24 + w0 + j] = fmaxf((yac[j] + bias) * s1 + o1, 0.f);
    tR[c * 24 + w0 + j] = (rv[j] + rbv) * sr + orr;
  }
  __syncthreads();
  size_t ob = ((size_t)bl * gT + t) * COUT * 24;
  for (int i = tid; i < COUT * 24 / 4; i += 256) {
    ((float4*)(y_out + ob))[i] = ((float4*)tY)[i];
    ((float4*)(r_out + ob))[i] = ((float4*)(tR))[i];
  }
}

// ============================= temporal conv =============================
// z[co,t,v] = sum_{ci,dt} y[ci,t+dt-2,v]*W[co,ci,dt]; + bias, bn2, +res, relu
template <int CIO, int CO_BLK, int NCO>
__global__ __launch_bounds__(256, 3) void k_tcn(
    const float* __restrict__ y_in,  // [Bc][T][CIO][24]
    const float* __restrict__ Wt,    // [(ci*5+dt)][CIO]
    const float* __restrict__ tb,
    const float* __restrict__ g2, const float* __restrict__ b2,
    const float* __restrict__ res,
    float* __restrict__ h_out)
{
  constexpr int CC = 8;               // ci per LDS tile
  constexpr int TTT = 8;              // t per block
  constexpr int ROWS = TTT + 4;       // halo'd rows
  constexpr int STRT = CC * 24 + 4;   // 196; mod 32 == 4 -> 2-way (free)
  constexpr int NCG = CO_BLK / NCO;   // co groups
  constexpr int TV = 256 / NCG;       // tv groups (16)
  __shared__ float yL[ROWS * STRT];
  __shared__ float WL[CC * 5 * CO_BLK];
  int t0 = blockIdx.x * TTT;
  int cob = blockIdx.y * CO_BLK;
  int bl = blockIdx.z;
  int tid = threadIdx.x;
  int g = tid % TV;
  int cg = tid / TV;
  int tt_own = g >> 1;
  int v0 = (g & 1) * 12;
  int co0 = cob + cg * NCO;
  float acc[NCO][12];
#pragma unroll
  for (int i = 0; i < NCO; ++i)
#pragma unroll
    for (int j = 0; j < 12; ++j) acc[i][j] = 0.f;

  const float* ybase = y_in + (size_t)bl * gT * CIO * 24;

  for (int ci0 = 0; ci0 < CIO; ci0 += CC) {
    __syncthreads();
    // stage y tile: ROWS x (CC ch x 24 v)
    for (int i = tid; i < ROWS * (CC * 24 / 4); i += 256) {
      int tt = i / (CC * 24 / 4), rf = i % (CC * 24 / 4);
      int tg = t0 - 2 + tt;
      float4 vv = make_float4(0.f, 0.f, 0.f, 0.f);
      if (tg >= 0 && tg < gT)
        vv = *(const float4*)(ybase + ((size_t)tg * CIO + ci0) * 24 + rf * 4);
      *(float4*)(&yL[tt * STRT + rf * 4]) = vv;
    }
    // stage W tile: [(cc*5+dt)][CO_BLK]
    for (int i = tid; i < CC * 5 * (CO_BLK / 4); i += 256) {
      int row = i / (CO_BLK / 4), cf = i % (CO_BLK / 4);
      *(float4*)(&WL[row * CO_BLK + cf * 4]) =
          *(const float4*)(Wt + ((size_t)ci0 * 5 + row) * CIO + cob + cf * 4);
    }
    __syncthreads();
    for (int cc = 0; cc < CC; ++cc) {
#pragma unroll
      for (int dt = 0; dt < 5; ++dt) {
        const float* wp = &WL[(cc * 5 + dt) * CO_BLK + cg * NCO];
        float wv[NCO];
#pragma unroll
        for (int q = 0; q < NCO / 4; ++q) {
          float4 w4 = *(const float4*)(wp + 4 * q);
          wv[4 * q + 0] = w4.x; wv[4 * q + 1] = w4.y; wv[4 * q + 2] = w4.z; wv[4 * q + 3] = w4.w;
        }
        const float* yp = &yL[(tt_own + dt) * STRT + cc * 24 + v0];
        float4 ya = *(const float4*)(yp);
        float4 yb = *(const float4*)(yp + 4);
        float4 yc = *(const float4*)(yp + 8);
        float yv[12] = {ya.x, ya.y, ya.z, ya.w, yb.x, yb.y, yb.z, yb.w, yc.x, yc.y, yc.z, yc.w};
#pragma unroll
        for (int i = 0; i < NCO; ++i)
#pragma unroll
          for (int j = 0; j < 12; ++j) acc[i][j] += wv[i] * yv[j];
      }
    }
  }

  int t = t0 + tt_own;
  size_t obase = ((size_t)bl * gT + t) * CIO * 24;
#pragma unroll
  for (int i = 0; i < NCO; ++i) {
    int co = co0 + i;
    float sc = BN_INV * g2[co], of = b2[co], bias = tb[co];
    float z[12];
#pragma unroll
    for (int j = 0; j < 12; ++j) z[j] = (acc[i][j] + bias) * sc + of;
    if (res != nullptr) {
#pragma unroll
      for (int q = 0; q < 3; ++q) {
        float4 r4 = *(const float4*)(res + obase + co * 24 + v0 + 4 * q);
        z[4 * q + 0] += r4.x; z[4 * q + 1] += r4.y; z[4 * q + 2] += r4.z; z[4 * q + 3] += r4.w;
      }
    }
#pragma unroll
    for (int q = 0; q < 3; ++q) {
      float4 o4;
      o4.x = fmaxf(z[4 * q + 0], 0.f);
      o4.y = fmaxf(z[4 * q + 1], 0.f);
      o4.z = fmaxf(z[4 * q + 2], 0.f);
      o4.w = fmaxf(z[4 * q + 3], 0.f);
      *(float4*)(h_out + obase + co * 24 + v0 + 4 * q) = o4;
    }
  }
}

// ============================= final FC =============================
__global__ __launch_bounds__(256) void k_fcn(
    const float* __restrict__ h,   // [Bc][T][64][24]
    const float* __restrict__ fw,  // [6][64]
    const float* __restrict__ fb,  // [6]
    float* __restrict__ out,       // [B][T][24][6]
    int b0)
{
  __shared__ float hLf[64 * 24];
  __shared__ float fwL[384];
  int t = blockIdx.x, bl = blockIdx.y, tid = threadIdx.x;
  int b = b0 + bl;
  const float* hb = h + ((size_t)bl * gT + t) * 64 * 24;
  for (int i = tid; i < 64 * 24 / 4; i += 256) ((float4*)hLf)[i] = ((const float4*)hb)[i];
  for (int i = tid; i < 384; i += 256) fwL[i] = fw[i];
  __syncthreads();
  if (tid < 144) {
    int v = tid / 6, o = tid % 6;
    float acc = fb[o];
#pragma unroll 8
    for (int cc = 0; cc < 64; ++cc) acc += hLf[cc * 24 + v] * fwL[o * 64 + cc];
    out[(((size_t)b * gT + t) * gV + v) * 6 + o] = acc;
  }
}

// ============================= host =============================
extern "C" void kernel_launch(void* const* d_in, const int* in_sizes, int n_in,
                              void* d_out, int out_size, void* d_ws, size_t ws_size,
                              hipStream_t stream) {
  const float* x    = (const float*)d_in[0];
  const float* A    = (const float*)d_in[1];
  const float* dbg  = (const float*)d_in[2];
  const float* dbb  = (const float*)d_in[3];
  const float* ei0  = (const float*)d_in[4];
  const float* ei1  = (const float*)d_in[5];
  const float* ei2  = (const float*)d_in[6];
  const float* w0g  = (const float*)d_in[7];
  const float* gb0  = (const float*)d_in[8];
  const float* g10  = (const float*)d_in[9];
  const float* b10  = (const float*)d_in[10];
  const float* tw0  = (const float*)d_in[11];
  const float* tb0  = (const float*)d_in[12];
  const float* g20  = (const float*)d_in[13];
  const float* b20  = (const float*)d_in[14];
  const float* w1g  = (const float*)d_in[15];
  const float* gb1  = (const float*)d_in[16];
  const float* g11  = (const float*)d_in[17];
  const float* b11  = (const float*)d_in[18];
  const float* tw1  = (const float*)d_in[19];
  const float* tb1  = (const float*)d_in[20];
  const float* g21  = (const float*)d_in[21];
  const float* b21  = (const float*)d_in[22];
  const float* rw1  = (const float*)d_in[23];
  const float* rb1  = (const float*)d_in[24];
  const float* rg1  = (const float*)d_in[25];
  const float* rbb1 = (const float*)d_in[26];
  const float* w2g  = (const float*)d_in[27];
  const float* gb2  = (const float*)d_in[28];
  const float* g12  = (const float*)d_in[29];
  const float* b12  = (const float*)d_in[30];
  const float* tw2  = (const float*)d_in[31];
  const float* tb2  = (const float*)d_in[32];
  const float* g22  = (const float*)d_in[33];
  const float* b22  = (const float*)d_in[34];
  const float* rw2  = (const float*)d_in[35];
  const float* rb2  = (const float*)d_in[36];
  const float* rg2  = (const float*)d_in[37];
  const float* rbb2 = (const float*)d_in[38];
  const float* fw   = (const float*)d_in[39];
  const float* fb   = (const float*)d_in[40];
  float* outp = (float*)d_out;
  float* ws = (float*)d_ws;

  size_t off = 0;
  auto alloc = [&](size_t n) { size_t o = off; off += n; return o; };
  size_t oAE = alloc(3 * 1728);
  size_t oCS = alloc(3 * 72);
  size_t oW1 = alloc((size_t)3 * 256 * 128);
  size_t oW2 = alloc((size_t)3 * 128 * 64);
  size_t oR1 = alloc((size_t)256 * 128);
  size_t oR2 = alloc((size_t)128 * 64);
  size_t oT0 = alloc((size_t)256 * 5 * 256);
  size_t oT1 = alloc((size_t)128 * 5 * 128);
  size_t oT2 = alloc((size_t)64 * 5 * 64);
  off = (off + 3) & ~(size_t)3;

  const size_t perB = (size_t)256 * gT * gV;
  int Bc = 32;
  while (Bc > 1 && (off + 2ull * perB * Bc) * 4ull > ws_size) Bc >>= 1;
  float* regA = ws + off;
  float* regB = regA + perB * Bc;

  // ---- prep ----
  k_prep_aeff<<<21, 256, 0, stream>>>(A, ei0, ei1, ei2, ws + oAE, ws + oCS);
  auto tgrid = [](int n) { return dim3((n + 255) / 256); };
  k_transpose<<<tgrid(3 * 256 * 128), 256, 0, stream>>>(w1g, ws + oW1, 3, 256, 128);
  k_transpose<<<tgrid(3 * 128 * 64), 256, 0, stream>>>(w2g, ws + oW2, 3, 128, 64);
  k_transpose<<<tgrid(256 * 128), 256, 0, stream>>>(rw1, ws + oR1, 1, 256, 128);
  k_transpose<<<tgrid(128 * 64), 256, 0, stream>>>(rw2, ws + oR2, 1, 128, 64);
  k_transpose<<<tgrid(256 * 5 * 256), 256, 0, stream>>>(tw0, ws + oT0, 1, 256 * 5, 256);
  k_transpose<<<tgrid(128 * 5 * 128), 256, 0, stream>>>(tw1, ws + oT1, 1, 128 * 5, 128);
  k_transpose<<<tgrid(64 * 5 * 64), 256, 0, stream>>>(tw2, ws + oT2, 1, 64 * 5, 64);

  for (int b0 = 0; b0 < 32; b0 += Bc) {
    dim3 gbt(gT, Bc);
    size_t r1off = (size_t)Bc * gT * 128 * 24;
    size_t r2off = (size_t)Bc * gT * 64 * 24;
    // layer 0
    k_gcn0<<<gbt, 256, 0, stream>>>(x, ws + oAE, ws + oCS, dbg, dbb, w0g, gb0, g10, b10, regB, b0);
    k_tcn<256, 128, 8><<<dim3(32, 2, Bc), 256, 0, stream>>>(regB, ws + oT0, tb0, g20, b20, nullptr, regA);
    // layer 1
    k_gcn12<256, 128><<<gbt, 256, 0, stream>>>(regA, ws + oAE + 1728, ws + oCS + 72, ws + oW1,
                                               gb1, g11, b11, ws + oR1, rb1, rg1, rbb1,
                                               regB, regB + r1off);
    k_tcn<128, 128, 8><<<dim3(32, 1, Bc), 256, 0, stream>>>(regB, ws + oT1, tb1, g21, b21, regB + r1off, regA);
    // layer 2
    k_gcn12<128, 64><<<gbt, 256, 0, stream>>>(regA, ws + oAE + 2 * 1728, ws + oCS + 144, ws + oW2,
                                              gb2, g12, b12, ws + oR2, rb2, rg2, rbb2,
                                              regB, regB + r2off);
    k_tcn<64, 64, 4><<<dim3(32, 1, Bc), 256, 0, stream>>>(regB, ws + oT2, tb2, g22, b22, regB + r2off, regA);
    // final FC
    k_fcn<<<gbt, 256, 0, stream>>>(regA, fw, fb, outp, b0);
  }
  (void)in_sizes; (void)n_in; (void)out_size;
}

// Round 4
// 3704.406 us; speedup vs baseline: 1.1345x; 1.1345x over previous
//
#include <hip/hip_runtime.h>

static constexpr int gT = 256;   // time steps
static constexpr int gV = 24;    // graph nodes
static constexpr float BN_INV = 0.99999500003749969f; // 1/sqrt(1+1e-5)

// ============================= prep kernels =============================
__global__ __launch_bounds__(256) void k_prep_aeff(
    const float* __restrict__ A, const float* __restrict__ e0,
    const float* __restrict__ e1, const float* __restrict__ e2,
    float* __restrict__ aeff, float* __restrict__ csum)
{
  int tid = blockIdx.x * 256 + threadIdx.x;
  if (tid < 3 * 1728) {
    int l = tid / 1728, r = tid % 1728;
    const float* e = (l == 0) ? e0 : ((l == 1) ? e1 : e2);
    aeff[tid] = A[r] * e[r];
  }
  if (tid < 3 * 72) {
    int l = tid / 72, r = tid % 72;
    int k = r / 24, w = r % 24;
    const float* e = (l == 0) ? e0 : ((l == 1) ? e1 : e2);
    float s = 0.f;
    for (int v = 0; v < 24; ++v) { int idx = (k * 24 + v) * 24 + w; s += A[idx] * e[idx]; }
    csum[tid] = s;
  }
}

// out[(k*Cin+ci)*Cout + c] = in[(k*Cout+c)*Cin + ci]
__global__ __launch_bounds__(256) void k_transpose(
    const float* __restrict__ in, float* __restrict__ out, int K, int Cin, int Cout)
{
  int idx = blockIdx.x * 256 + threadIdx.x;
  int total = K * Cin * Cout;
  if (idx >= total) return;
  int kk = idx / Cout, c = idx % Cout;
  int k = kk / Cin, ci = kk % Cin;
  out[idx] = in[(size_t)(k * Cout + c) * Cin + ci];
}

// ============================= layer 0 GCN =============================
__global__ __launch_bounds__(256) void k_gcn0(
    const float* __restrict__ x,      // [B][T][24][3]
    const float* __restrict__ aeff,   // [3][24][24]
    const float* __restrict__ csum,   // [3][24]
    const float* __restrict__ dbg, const float* __restrict__ dbb,  // [72]
    const float* __restrict__ W0,     // [768][3]
    const float* __restrict__ gb0,    // [768]
    const float* __restrict__ g1, const float* __restrict__ b1,    // [256]
    float* __restrict__ y_out,        // [Bc][T][256][24]
    int b0)
{
  __shared__ float xbn[72];      // [cin][v]
  __shared__ float XA[216];      // [(k*3+ci)][w]
  __shared__ float WL[2304];
  __shared__ float tile[256 * 25];
  int t = blockIdx.x, bl = blockIdx.y, tid = threadIdx.x;
  int b = b0 + bl;

  if (tid < 72) {
    int v = tid / 3, cin = tid % 3;
    float xv = x[(((size_t)b * gT + t) * gV + v) * 3 + cin];
    xbn[cin * 24 + v] = xv * (BN_INV * dbg[tid]) + dbb[tid];
  }
  for (int i = tid; i < 2304; i += 256) WL[i] = W0[i];
  __syncthreads();

  if (tid < 216) {
    int k = tid / 72, r = tid % 72, ci = r / 24, w = r % 24;
    const float* Ak = aeff + k * 576;
    float s = 0.f;
#pragma unroll
    for (int v = 0; v < 24; ++v) s += xbn[ci * 24 + v] * Ak[v * 24 + w];
    XA[tid] = s;
  }
  __syncthreads();

  int c = tid;
  float acc[24];
#pragma unroll
  for (int w = 0; w < 24; ++w) acc[w] = 0.f;
#pragma unroll
  for (int k = 0; k < 3; ++k) {
#pragma unroll
    for (int ci = 0; ci < 3; ++ci) {
      float wv = WL[(k * 256 + c) * 3 + ci];
#pragma unroll
      for (int w = 0; w < 24; ++w) acc[w] += wv * XA[(k * 3 + ci) * 24 + w];
    }
    float gv = gb0[k * 256 + c];
#pragma unroll
    for (int w = 0; w < 24; ++w) acc[w] += gv * csum[k * 24 + w];
  }
  float s1 = BN_INV * g1[c], o1 = b1[c];
#pragma unroll
  for (int w = 0; w < 24; ++w) tile[c * 25 + w] = fmaxf(acc[w] * s1 + o1, 0.f);
  __syncthreads();

  float* ob = y_out + ((size_t)bl * gT + t) * 6144;
#pragma unroll
  for (int i = 0; i < 6; ++i) {
    int f4 = i * 256 + tid;
    int f = f4 * 4;
    float4 vv;
    vv.x = tile[((f + 0) / 24) * 25 + (f + 0) % 24];
    vv.y = tile[((f + 1) / 24) * 25 + (f + 1) % 24];
    vv.z = tile[((f + 2) / 24) * 25 + (f + 2) % 24];
    vv.w = tile[((f + 3) / 24) * 25 + (f + 3) % 24];
    ((float4*)ob)[f4] = vv;
  }
}

// ============================= layers 1,2 GCN + residual =============================
// R2 formulation (issue-bound, ~108% VALUBusy): XA-first per k, coalesced W rows,
// LDS-broadcast inner loop.  R3's W-first variant regressed to VALUBusy 22%
// (scalar stride-COUT global W loads, serial slice-reduce) — reverted.
template <int CIN, int COUT>
__global__ __launch_bounds__(256) void k_gcn12(
    const float* __restrict__ h_in,   // [Bc][T][CIN][24]
    const float* __restrict__ aeffL,  // [3][24][24]
    const float* __restrict__ csumL,  // [3][24]
    const float* __restrict__ Wg,     // transposed: [(k*CIN+ci)][COUT]
    const float* __restrict__ gb,     // [3*COUT]
    const float* __restrict__ g1, const float* __restrict__ b1,
    const float* __restrict__ Wr,     // transposed: [ci][COUT]
    const float* __restrict__ rb, const float* __restrict__ rg, const float* __restrict__ rbb,
    float* __restrict__ y_out,        // [Bc][T][COUT][24]
    float* __restrict__ r_out)        // [Bc][T][COUT][24]
{
  __shared__ float hL[CIN * 24];
  __shared__ float XAk[CIN * 24];
  int t = blockIdx.x, bl = blockIdx.y, tid = threadIdx.x;
  const float* hbase = h_in + ((size_t)bl * gT + t) * CIN * 24;
  for (int i = tid; i < CIN * 24 / 4; i += 256)
    ((float4*)hL)[i] = ((const float4*)hbase)[i];
  __syncthreads();

  int wt = tid & 7, ct = tid >> 3;   // wt: 8 w-groups of 3; ct: 32 c-groups
  int w0 = wt * 3;
  constexpr int NI = COUT / 32;
  float accR[NI][3];
  float accY[NI][3];
#pragma unroll
  for (int i = 0; i < NI; ++i)
#pragma unroll
    for (int j = 0; j < 3; ++j) { accR[i][j] = 0.f; accY[i][j] = 0.f; }

  // residual 1x1 conv
#pragma unroll 4
  for (int ci = 0; ci < CIN; ++ci) {
    float x0 = hL[ci * 24 + w0], x1 = hL[ci * 24 + w0 + 1], x2 = hL[ci * 24 + w0 + 2];
    const float* wrow = Wr + (size_t)ci * COUT + ct;
#pragma unroll
    for (int i = 0; i < NI; ++i) {
      float wv = wrow[32 * i];
      accR[i][0] += wv * x0; accR[i][1] += wv * x1; accR[i][2] += wv * x2;
    }
  }

  // gcn: for each k, build XA then accumulate GEMM
  for (int k = 0; k < 3; ++k) {
    __syncthreads();
    if (tid < CIN) {
      int ci = tid;
      float hr[24];
#pragma unroll
      for (int v = 0; v < 24; ++v) hr[v] = hL[ci * 24 + v];
      const float* Ak = aeffL + k * 576;
      for (int w = 0; w < 24; ++w) {
        float s = 0.f;
#pragma unroll
        for (int v = 0; v < 24; ++v) s += hr[v] * Ak[v * 24 + w];
        XAk[ci * 24 + w] = s;
      }
    }
    __syncthreads();
    const float* Wk = Wg + (size_t)k * CIN * COUT;
#pragma unroll 4
    for (int ci = 0; ci < CIN; ++ci) {
      float x0 = XAk[ci * 24 + w0], x1 = XAk[ci * 24 + w0 + 1], x2 = XAk[ci * 24 + w0 + 2];
      const float* wrow = Wk + (size_t)ci * COUT + ct;
#pragma unroll
      for (int i = 0; i < NI; ++i) {
        float wv = wrow[32 * i];
        accY[i][0] += wv * x0; accY[i][1] += wv * x1; accY[i][2] += wv * x2;
      }
    }
  }

  __syncthreads();
  float* tY = XAk;  // reuse LDS for coalesced write staging
  float* tR = hL;
#pragma unroll
  for (int i = 0; i < NI; ++i) {
    int c = ct + 32 * i;
    float bias[3] = {0.f, 0.f, 0.f};
#pragma unroll
    for (int k = 0; k < 3; ++k) {
      float gv = gb[k * COUT + c];
      bias[0] += gv * csumL[k * 24 + w0];
      bias[1] += gv * csumL[k * 24 + w0 + 1];
      bias[2] += gv * csumL[k * 24 + w0 + 2];
    }
    float s1 = BN_INV * g1[c], o1 = b1[c];
    float sr = BN_INV * rg[c], orr = rbb[c], rbv = rb[c];
#pragma unroll
    for (int j = 0; j < 3; ++j) {
      tY[c * 24 + w0 + j] = fmaxf((accY[i][j] + bias[j]) * s1 + o1, 0.f);
      tR[c * 24 + w0 + j] = (accR[i][j] + rbv) * sr + orr;
    }
  }
  __syncthreads();
  size_t ob = ((size_t)bl * gT + t) * COUT * 24;
  for (int i = tid; i < COUT * 24 / 4; i += 256) {
    ((float4*)(y_out + ob))[i] = ((float4*)tY)[i];
    ((float4*)(r_out + ob))[i] = ((float4*)tR)[i];
  }
}

// ============================= temporal conv =============================
// R3 version (kept): 8co x 12tv per thread, CC=8 -> 96 FMA per 5 LDS b128 reads.
template <int CIO, int CO_BLK, int NCO>
__global__ __launch_bounds__(256, 3) void k_tcn(
    const float* __restrict__ y_in,  // [Bc][T][CIO][24]
    const float* __restrict__ Wt,    // [(ci*5+dt)][CIO]
    const float* __restrict__ tb,
    const float* __restrict__ g2, const float* __restrict__ b2,
    const float* __restrict__ res,
    float* __restrict__ h_out)
{
  constexpr int CC = 8;               // ci per LDS tile
  constexpr int TTT = 8;              // t per block
  constexpr int ROWS = TTT + 4;       // halo'd rows
  constexpr int STRT = CC * 24 + 4;   // 196; mod 32 == 4 -> 2-way (free)
  constexpr int NCG = CO_BLK / NCO;   // co groups
  constexpr int TV = 256 / NCG;       // tv groups (16)
  __shared__ float yL[ROWS * STRT];
  __shared__ float WL[CC * 5 * CO_BLK];
  int t0 = blockIdx.x * TTT;
  int cob = blockIdx.y * CO_BLK;
  int bl = blockIdx.z;
  int tid = threadIdx.x;
  int g = tid % TV;
  int cg = tid / TV;
  int tt_own = g >> 1;
  int v0 = (g & 1) * 12;
  int co0 = cob + cg * NCO;
  float acc[NCO][12];
#pragma unroll
  for (int i = 0; i < NCO; ++i)
#pragma unroll
    for (int j = 0; j < 12; ++j) acc[i][j] = 0.f;

  const float* ybase = y_in + (size_t)bl * gT * CIO * 24;

  for (int ci0 = 0; ci0 < CIO; ci0 += CC) {
    __syncthreads();
    // stage y tile: ROWS x (CC ch x 24 v)
    for (int i = tid; i < ROWS * (CC * 24 / 4); i += 256) {
      int tt = i / (CC * 24 / 4), rf = i % (CC * 24 / 4);
      int tg = t0 - 2 + tt;
      float4 vv = make_float4(0.f, 0.f, 0.f, 0.f);
      if (tg >= 0 && tg < gT)
        vv = *(const float4*)(ybase + ((size_t)tg * CIO + ci0) * 24 + rf * 4);
      *(float4*)(&yL[tt * STRT + rf * 4]) = vv;
    }
    // stage W tile: [(cc*5+dt)][CO_BLK]
    for (int i = tid; i < CC * 5 * (CO_BLK / 4); i += 256) {
      int row = i / (CO_BLK / 4), cf = i % (CO_BLK / 4);
      *(float4*)(&WL[row * CO_BLK + cf * 4]) =
          *(const float4*)(Wt + ((size_t)ci0 * 5 + row) * CIO + cob + cf * 4);
    }
    __syncthreads();
    for (int cc = 0; cc < CC; ++cc) {
#pragma unroll
      for (int dt = 0; dt < 5; ++dt) {
        const float* wp = &WL[(cc * 5 + dt) * CO_BLK + cg * NCO];
        float wv[NCO];
#pragma unroll
        for (int q = 0; q < NCO / 4; ++q) {
          float4 w4 = *(const float4*)(wp + 4 * q);
          wv[4 * q + 0] = w4.x; wv[4 * q + 1] = w4.y; wv[4 * q + 2] = w4.z; wv[4 * q + 3] = w4.w;
        }
        const float* yp = &yL[(tt_own + dt) * STRT + cc * 24 + v0];
        float4 ya = *(const float4*)(yp);
        float4 yb = *(const float4*)(yp + 4);
        float4 yc = *(const float4*)(yp + 8);
        float yv[12] = {ya.x, ya.y, ya.z, ya.w, yb.x, yb.y, yb.z, yb.w, yc.x, yc.y, yc.z, yc.w};
#pragma unroll
        for (int i = 0; i < NCO; ++i)
#pragma unroll
          for (int j = 0; j < 12; ++j) acc[i][j] += wv[i] * yv[j];
      }
    }
  }

  int t = t0 + tt_own;
  size_t obase = ((size_t)bl * gT + t) * CIO * 24;
#pragma unroll
  for (int i = 0; i < NCO; ++i) {
    int co = co0 + i;
    float sc = BN_INV * g2[co], of = b2[co], bias = tb[co];
    float z[12];
#pragma unroll
    for (int j = 0; j < 12; ++j) z[j] = (acc[i][j] + bias) * sc + of;
    if (res != nullptr) {
#pragma unroll
      for (int q = 0; q < 3; ++q) {
        float4 r4 = *(const float4*)(res + obase + co * 24 + v0 + 4 * q);
        z[4 * q + 0] += r4.x; z[4 * q + 1] += r4.y; z[4 * q + 2] += r4.z; z[4 * q + 3] += r4.w;
      }
    }
#pragma unroll
    for (int q = 0; q < 3; ++q) {
      float4 o4;
      o4.x = fmaxf(z[4 * q + 0], 0.f);
      o4.y = fmaxf(z[4 * q + 1], 0.f);
      o4.z = fmaxf(z[4 * q + 2], 0.f);
      o4.w = fmaxf(z[4 * q + 3], 0.f);
      *(float4*)(h_out + obase + co * 24 + v0 + 4 * q) = o4;
    }
  }
}

// ============================= final FC =============================
__global__ __launch_bounds__(256) void k_fcn(
    const float* __restrict__ h,   // [Bc][T][64][24]
    const float* __restrict__ fw,  // [6][64]
    const float* __restrict__ fb,  // [6]
    float* __restrict__ out,       // [B][T][24][6]
    int b0)
{
  __shared__ float hLf[64 * 24];
  __shared__ float fwL[384];
  int t = blockIdx.x, bl = blockIdx.y, tid = threadIdx.x;
  int b = b0 + bl;
  const float* hb = h + ((size_t)bl * gT + t) * 64 * 24;
  for (int i = tid; i < 64 * 24 / 4; i += 256) ((float4*)hLf)[i] = ((const float4*)hb)[i];
  for (int i = tid; i < 384; i += 256) fwL[i] = fw[i];
  __syncthreads();
  if (tid < 144) {
    int v = tid / 6, o = tid % 6;
    float acc = fb[o];
#pragma unroll 8
    for (int cc = 0; cc < 64; ++cc) acc += hLf[cc * 24 + v] * fwL[o * 64 + cc];
    out[(((size_t)b * gT + t) * gV + v) * 6 + o] = acc;
  }
}

// ============================= host =============================
extern "C" void kernel_launch(void* const* d_in, const int* in_sizes, int n_in,
                              void* d_out, int out_size, void* d_ws, size_t ws_size,
                              hipStream_t stream) {
  const float* x    = (const float*)d_in[0];
  const float* A    = (const float*)d_in[1];
  const float* dbg  = (const float*)d_in[2];
  const float* dbb  = (const float*)d_in[3];
  const float* ei0  = (const float*)d_in[4];
  const float* ei1  = (const float*)d_in[5];
  const float* ei2  = (const float*)d_in[6];
  const float* w0g  = (const float*)d_in[7];
  const float* gb0  = (const float*)d_in[8];
  const float* g10  = (const float*)d_in[9];
  const float* b10  = (const float*)d_in[10];
  const float* tw0  = (const float*)d_in[11];
  const float* tb0  = (const float*)d_in[12];
  const float* g20  = (const float*)d_in[13];
  const float* b20  = (const float*)d_in[14];
  const float* w1g  = (const float*)d_in[15];
  const float* gb1  = (const float*)d_in[16];
  const float* g11  = (const float*)d_in[17];
  const float* b11  = (const float*)d_in[18];
  const float* tw1  = (const float*)d_in[19];
  const float* tb1  = (const float*)d_in[20];
  const float* g21  = (const float*)d_in[21];
  const float* b21  = (const float*)d_in[22];
  const float* rw1  = (const float*)d_in[23];
  const float* rb1  = (const float*)d_in[24];
  const float* rg1  = (const float*)d_in[25];
  const float* rbb1 = (const float*)d_in[26];
  const float* w2g  = (const float*)d_in[27];
  const float* gb2  = (const float*)d_in[28];
  const float* g12  = (const float*)d_in[29];
  const float* b12  = (const float*)d_in[30];
  const float* tw2  = (const float*)d_in[31];
  const float* tb2  = (const float*)d_in[32];
  const float* g22  = (const float*)d_in[33];
  const float* b22  = (const float*)d_in[34];
  const float* rw2  = (const float*)d_in[35];
  const float* rb2  = (const float*)d_in[36];
  const float* rg2  = (const float*)d_in[37];
  const float* rbb2 = (const float*)d_in[38];
  const float* fw   = (const float*)d_in[39];
  const float* fb   = (const float*)d_in[40];
  float* outp = (float*)d_out;
  float* ws = (float*)d_ws;

  size_t off = 0;
  auto alloc = [&](size_t n) { size_t o = off; off += n; return o; };
  size_t oAE = alloc(3 * 1728);
  size_t oCS = alloc(3 * 72);
  size_t oW1 = alloc((size_t)3 * 256 * 128);
  size_t oW2 = alloc((size_t)3 * 128 * 64);
  size_t oR1 = alloc((size_t)256 * 128);
  size_t oR2 = alloc((size_t)128 * 64);
  size_t oT0 = alloc((size_t)256 * 5 * 256);
  size_t oT1 = alloc((size_t)128 * 5 * 128);
  size_t oT2 = alloc((size_t)64 * 5 * 64);
  off = (off + 3) & ~(size_t)3;

  const size_t perB = (size_t)256 * gT * gV;
  int Bc = 32;
  while (Bc > 1 && (off + 2ull * perB * Bc) * 4ull > ws_size) Bc >>= 1;
  float* regA = ws + off;
  float* regB = regA + perB * Bc;

  // ---- prep ----
  k_prep_aeff<<<21, 256, 0, stream>>>(A, ei0, ei1, ei2, ws + oAE, ws + oCS);
  auto tgrid = [](int n) { return dim3((n + 255) / 256); };
  k_transpose<<<tgrid(3 * 256 * 128), 256, 0, stream>>>(w1g, ws + oW1, 3, 256, 128);
  k_transpose<<<tgrid(3 * 128 * 64), 256, 0, stream>>>(w2g, ws + oW2, 3, 128, 64);
  k_transpose<<<tgrid(256 * 128), 256, 0, stream>>>(rw1, ws + oR1, 1, 256, 128);
  k_transpose<<<tgrid(128 * 64), 256, 0, stream>>>(rw2, ws + oR2, 1, 128, 64);
  k_transpose<<<tgrid(256 * 5 * 256), 256, 0, stream>>>(tw0, ws + oT0, 1, 256 * 5, 256);
  k_transpose<<<tgrid(128 * 5 * 128), 256, 0, stream>>>(tw1, ws + oT1, 1, 128 * 5, 128);
  k_transpose<<<tgrid(64 * 5 * 64), 256, 0, stream>>>(tw2, ws + oT2, 1, 64 * 5, 64);

  for (int b0 = 0; b0 < 32; b0 += Bc) {
    dim3 gbt(gT, Bc);
    size_t r1off = (size_t)Bc * gT * 128 * 24;
    size_t r2off = (size_t)Bc * gT * 64 * 24;
    // layer 0
    k_gcn0<<<gbt, 256, 0, stream>>>(x, ws + oAE, ws + oCS, dbg, dbb, w0g, gb0, g10, b10, regB, b0);
    k_tcn<256, 128, 8><<<dim3(32, 2, Bc), 256, 0, stream>>>(regB, ws + oT0, tb0, g20, b20, nullptr, regA);
    // layer 1
    k_gcn12<256, 128><<<gbt, 256, 0, stream>>>(regA, ws + oAE + 1728, ws + oCS + 72, ws + oW1,
                                               gb1, g11, b11, ws + oR1, rb1, rg1, rbb1,
                                               regB, regB + r1off);
    k_tcn<128, 128, 8><<<dim3(32, 1, Bc), 256, 0, stream>>>(regB, ws + oT1, tb1, g21, b21, regB + r1off, regA);
    // layer 2
    k_gcn12<128, 64><<<gbt, 256, 0, stream>>>(regA, ws + oAE + 2 * 1728, ws + oCS + 144, ws + oW2,
                                              gb2, g12, b12, ws + oR2, rb2, rg2, rbb2,
                                              regB, regB + r2off);
    k_tcn<64, 64, 4><<<dim3(32, 1, Bc), 256, 0, stream>>>(regB, ws + oT2, tb2, g22, b22, regB + r2off, regA);
    // final FC
    k_fcn<<<gbt, 256, 0, stream>>>(regA, fw, fb, outp, b0);
  }
  (void)in_sizes; (void)n_in; (void)out_size;
}

// Round 6
// 2435.318 us; speedup vs baseline: 1.7257x; 1.5211x over previous
//
#include <hip/hip_runtime.h>

typedef _Float16 half8 __attribute__((ext_vector_type(8)));
typedef _Float16 half2v __attribute__((ext_vector_type(2)));
typedef float floatx16 __attribute__((ext_vector_type(16)));

static constexpr int gT = 256;   // time steps
static constexpr int gV = 24;    // graph nodes
static constexpr int gN = gT * gV;  // 6144 columns per batch
static constexpr float BN_INV = 0.99999500003749969f; // 1/sqrt(1+1e-5)

// ============================= prep kernels =============================
__global__ __launch_bounds__(256) void k_prep_aeff(
    const float* __restrict__ A, const float* __restrict__ e0,
    const float* __restrict__ e1, const float* __restrict__ e2,
    float* __restrict__ aeff, float* __restrict__ csum)
{
  int tid = blockIdx.x * 256 + threadIdx.x;
  if (tid < 3 * 1728) {
    int l = tid / 1728, r = tid % 1728;
    const float* e = (l == 0) ? e0 : ((l == 1) ? e1 : e2);
    aeff[tid] = A[r] * e[r];
  }
  if (tid < 3 * 72) {
    int l = tid / 72, r = tid % 72;
    int k = r / 24, w = r % 24;
    const float* e = (l == 0) ? e0 : ((l == 1) ? e1 : e2);
    float s = 0.f;
    for (int v = 0; v < 24; ++v) { int idx = (k * 24 + v) * 24 + w; s += A[idx] * e[idx]; }
    csum[tid] = s;
  }
}

// out[(k*Cin+ci)*Cout + c] = in[(k*Cout+c)*Cin + ci]
__global__ __launch_bounds__(256) void k_transpose(
    const float* __restrict__ in, float* __restrict__ out, int K, int Cin, int Cout)
{
  int idx = blockIdx.x * 256 + threadIdx.x;
  int total = K * Cin * Cout;
  if (idx >= total) return;
  int kk = idx / Cout, c = idx % Cout;
  int k = kk / Cin, ci = kk % Cin;
  out[idx] = in[(size_t)(k * Cout + c) * Cin + ci];
}

// Pack tcn weights into MFMA A-fragment order, f16 hi/lo split.
// frag id = ((((mt*KT + kt)*2 + ks)*5 + dt)*2 + pl); lane l: m = mt*32+(l&31),
// k(ci) = kt*32 + ks*16 + (l>>5)*8 + e  (v_mfma_f32_32x32x16_f16 A layout).
__global__ __launch_bounds__(256) void k_prep_twf(
    const float* __restrict__ tw, _Float16* __restrict__ out, int CI, int KT)
{
  int g = blockIdx.x * 256 + threadIdx.x;
  int fid = g >> 6, lane = g & 63;
  int pl = fid & 1;
  int f2 = fid >> 1;
  int dt = f2 % 5;
  int f3 = f2 / 5;
  int ks = f3 & 1;
  int f4 = f3 >> 1;
  int kt = f4 % KT;
  int mt = f4 / KT;
  int m = mt * 32 + (lane & 31);
  int kb = kt * 32 + ks * 16 + ((lane >> 5) << 3);
  half8 o;
#pragma unroll
  for (int e = 0; e < 8; ++e) {
    float v = tw[((size_t)m * CI + (kb + e)) * 5 + dt];
    _Float16 h = (_Float16)v;
    o[e] = pl ? (_Float16)(v - (float)h) : h;
  }
  *(half8*)(out + ((size_t)fid * 64 + lane) * 8) = o;
}

// ============================= layer 0 GCN =============================
// fused data_bn + gcn(3->256) + bn1 + relu; emits f16 hi/lo planes [t][v][256]
__global__ __launch_bounds__(256) void k_gcn0(
    const float* __restrict__ x,      // [B][T][24][3]
    const float* __restrict__ aeff,   // [3][24][24]
    const float* __restrict__ csum,   // [3][24]
    const float* __restrict__ dbg, const float* __restrict__ dbb,  // [72]
    const float* __restrict__ W0,     // [768][3]
    const float* __restrict__ gb0,    // [768]
    const float* __restrict__ g1, const float* __restrict__ b1,    // [256]
    _Float16* __restrict__ yh, _Float16* __restrict__ yl,          // [Bc][6144][256]
    int b0)
{
  __shared__ float xbn[72];      // [cin][v]
  __shared__ float XA[216];      // [(k*3+ci)][w]
  __shared__ float WL[2304];
  __shared__ float tile[256 * 25];
  int t = blockIdx.x, bl = blockIdx.y, tid = threadIdx.x;
  int b = b0 + bl;

  if (tid < 72) {
    int v = tid / 3, cin = tid % 3;
    float xv = x[(((size_t)b * gT + t) * gV + v) * 3 + cin];
    xbn[cin * 24 + v] = xv * (BN_INV * dbg[tid]) + dbb[tid];
  }
  for (int i = tid; i < 2304; i += 256) WL[i] = W0[i];
  __syncthreads();

  if (tid < 216) {
    int k = tid / 72, r = tid % 72, ci = r / 24, w = r % 24;
    const float* Ak = aeff + k * 576;
    float s = 0.f;
#pragma unroll
    for (int v = 0; v < 24; ++v) s += xbn[ci * 24 + v] * Ak[v * 24 + w];
    XA[tid] = s;
  }
  __syncthreads();

  int c = tid;
  float acc[24];
#pragma unroll
  for (int w = 0; w < 24; ++w) acc[w] = 0.f;
#pragma unroll
  for (int k = 0; k < 3; ++k) {
#pragma unroll
    for (int ci = 0; ci < 3; ++ci) {
      float wv = WL[(k * 256 + c) * 3 + ci];
#pragma unroll
      for (int w = 0; w < 24; ++w) acc[w] += wv * XA[(k * 3 + ci) * 24 + w];
    }
    float gv = gb0[k * 256 + c];
#pragma unroll
    for (int w = 0; w < 24; ++w) acc[w] += gv * csum[k * 24 + w];
  }
  float s1 = BN_INV * g1[c], o1 = b1[c];
#pragma unroll
  for (int w = 0; w < 24; ++w) tile[c * 25 + w] = fmaxf(acc[w] * s1 + o1, 0.f);
  __syncthreads();

  // write hi/lo planes, n-major: y[(t*24+w)*256 + c]
  size_t nb = ((size_t)bl * gN + (size_t)t * 24);
#pragma unroll
  for (int it = 0; it < 12; ++it) {
    int idx = it * 256 + tid;          // < 3072
    int w = idx >> 7;                  // /128
    int c0 = (idx & 127) * 2;
    float v0 = tile[c0 * 25 + w], v1 = tile[(c0 + 1) * 25 + w];
    _Float16 h0 = (_Float16)v0, h1 = (_Float16)v1;
    _Float16 l0 = (_Float16)(v0 - (float)h0), l1 = (_Float16)(v1 - (float)h1);
    size_t a = (nb + w) * 256 + c0;
    half2v ph; ph[0] = h0; ph[1] = h1;
    half2v plv; plv[0] = l0; plv[1] = l1;
    *(half2v*)(yh + a) = ph;
    *(half2v*)(yl + a) = plv;
  }
}

// ============================= layers 1,2 GCN + residual =============================
// XA-first fp32 formulation (R2, issue-bound).  Emits y as f16 hi/lo planes
// [t][v][COUT] for the MFMA tcn, and r as fp32 [t][COUT][24].
template <int CIN, int COUT>
__global__ __launch_bounds__(256) void k_gcn12(
    const float* __restrict__ h_in,   // [Bc][T][CIN][24]
    const float* __restrict__ aeffL,  // [3][24][24]
    const float* __restrict__ csumL,  // [3][24]
    const float* __restrict__ Wg,     // transposed: [(k*CIN+ci)][COUT]
    const float* __restrict__ gb,     // [3*COUT]
    const float* __restrict__ g1, const float* __restrict__ b1,
    const float* __restrict__ Wr,     // transposed: [ci][COUT]
    const float* __restrict__ rb, const float* __restrict__ rg, const float* __restrict__ rbb,
    _Float16* __restrict__ yh, _Float16* __restrict__ yl,  // [Bc][6144][COUT]
    float* __restrict__ r_out)        // [Bc][T][COUT][24]
{
  __shared__ float hL[CIN * 24];
  __shared__ float XAk[CIN * 24];
  int t = blockIdx.x, bl = blockIdx.y, tid = threadIdx.x;
  const float* hbase = h_in + ((size_t)bl * gT + t) * CIN * 24;
  for (int i = tid; i < CIN * 24 / 4; i += 256)
    ((float4*)hL)[i] = ((const float4*)hbase)[i];
  __syncthreads();

  int wt = tid & 7, ct = tid >> 3;   // wt: 8 w-groups of 3; ct: 32 c-groups
  int w0 = wt * 3;
  constexpr int NI = COUT / 32;
  float accR[NI][3];
  float accY[NI][3];
#pragma unroll
  for (int i = 0; i < NI; ++i)
#pragma unroll
    for (int j = 0; j < 3; ++j) { accR[i][j] = 0.f; accY[i][j] = 0.f; }

  // residual 1x1 conv
#pragma unroll 4
  for (int ci = 0; ci < CIN; ++ci) {
    float x0 = hL[ci * 24 + w0], x1 = hL[ci * 24 + w0 + 1], x2 = hL[ci * 24 + w0 + 2];
    const float* wrow = Wr + (size_t)ci * COUT + ct;
#pragma unroll
    for (int i = 0; i < NI; ++i) {
      float wv = wrow[32 * i];
      accR[i][0] += wv * x0; accR[i][1] += wv * x1; accR[i][2] += wv * x2;
    }
  }

  // gcn: for each k, build XA then accumulate GEMM
  for (int k = 0; k < 3; ++k) {
    __syncthreads();
    if (tid < CIN) {
      int ci = tid;
      float hr[24];
#pragma unroll
      for (int v = 0; v < 24; ++v) hr[v] = hL[ci * 24 + v];
      const float* Ak = aeffL + k * 576;
      for (int w = 0; w < 24; ++w) {
        float s = 0.f;
#pragma unroll
        for (int v = 0; v < 24; ++v) s += hr[v] * Ak[v * 24 + w];
        XAk[ci * 24 + w] = s;
      }
    }
    __syncthreads();
    const float* Wk = Wg + (size_t)k * CIN * COUT;
#pragma unroll 4
    for (int ci = 0; ci < CIN; ++ci) {
      float x0 = XAk[ci * 24 + w0], x1 = XAk[ci * 24 + w0 + 1], x2 = XAk[ci * 24 + w0 + 2];
      const float* wrow = Wk + (size_t)ci * COUT + ct;
#pragma unroll
      for (int i = 0; i < NI; ++i) {
        float wv = wrow[32 * i];
        accY[i][0] += wv * x0; accY[i][1] += wv * x1; accY[i][2] += wv * x2;
      }
    }
  }

  __syncthreads();
  float* tY = XAk;  // stride-25 padded staging for transposed plane write
  float* tR = hL;
#pragma unroll
  for (int i = 0; i < NI; ++i) {
    int c = ct + 32 * i;
    float bias[3] = {0.f, 0.f, 0.f};
#pragma unroll
    for (int k = 0; k < 3; ++k) {
      float gv = gb[k * COUT + c];
      bias[0] += gv * csumL[k * 24 + w0];
      bias[1] += gv * csumL[k * 24 + w0 + 1];
      bias[2] += gv * csumL[k * 24 + w0 + 2];
    }
    float s1 = BN_INV * g1[c], o1 = b1[c];
    float sr = BN_INV * rg[c], orr = rbb[c], rbv = rb[c];
#pragma unroll
    for (int j = 0; j < 3; ++j) {
      tY[c * 25 + w0 + j] = fmaxf((accY[i][j] + bias[j]) * s1 + o1, 0.f);
      tR[c * 24 + w0 + j] = (accR[i][j] + rbv) * sr + orr;
    }
  }
  __syncthreads();
  // r: fp32 [t][COUT][24] contiguous
  size_t ob = ((size_t)bl * gT + t) * COUT * 24;
  for (int i = tid; i < COUT * 24 / 4; i += 256)
    ((float4*)(r_out + ob))[i] = ((float4*)tR)[i];
  // y: hi/lo planes, n-major [t*24+w][COUT]
  size_t nb = ((size_t)bl * gN + (size_t)t * 24);
  constexpr int HC = COUT / 2;
  constexpr int YIT = (24 * HC) / 256;
#pragma unroll
  for (int it = 0; it < YIT; ++it) {
    int idx = it * 256 + tid;
    int w = idx / HC;
    int c0 = (idx % HC) * 2;
    float v0 = tY[c0 * 25 + w], v1 = tY[(c0 + 1) * 25 + w];
    _Float16 h0 = (_Float16)v0, h1 = (_Float16)v1;
    _Float16 l0 = (_Float16)(v0 - (float)h0), l1 = (_Float16)(v1 - (float)h1);
    size_t a = (nb + w) * COUT + c0;
    half2v ph; ph[0] = h0; ph[1] = h1;
    half2v plv; plv[0] = l0; plv[1] = l1;
    *(half2v*)(yh + a) = ph;
    *(half2v*)(yl + a) = plv;
  }
}

// ============================= temporal conv (MFMA) =============================
// C[co, n=(t,v)] = sum_dt A_dt[co,ci] @ B[ci, n+(dt-2)*24]  per batch.
// B staged in LDS [n_local][ci] (pitch 40 halves), halo rows cover dt shifts.
// 3 MFMA per logical product: hh + hl + lh (f16 hi/lo split).
template <int CIO, int MF>
__global__ __launch_bounds__(256) void k_tcn_mfma(
    const _Float16* __restrict__ yH, const _Float16* __restrict__ yL, // [b][n][CIO]
    const _Float16* __restrict__ Apack,
    const float* __restrict__ tb,
    const float* __restrict__ g2, const float* __restrict__ b2,
    const float* __restrict__ res,   // [b][t][CIO][24] fp32 or nullptr
    float* __restrict__ h_out)       // [b][t][CIO][24]
{
  constexpr int KT = CIO / 32;
  constexpr int M_BLK = MF * 64;
  constexpr int NROW = 224, KP = 40;
  __shared__ _Float16 BH[NROW * KP];
  __shared__ _Float16 BL[NROW * KP];
  __shared__ float scL[CIO], ofL[CIO], tbL[CIO];
  int bx = blockIdx.x, mb = blockIdx.y, bl = blockIdx.z;
  int tid = threadIdx.x;
  int w = tid >> 6, lane = tid & 63;
  int n0 = bx * 128;

  for (int i = tid; i < CIO; i += 256) {
    scL[i] = BN_INV * g2[i]; ofL[i] = b2[i]; tbL[i] = tb[i];
  }

  floatx16 acc[MF][2] = {};

  const _Float16* ybH = yH + (size_t)bl * gN * CIO;
  const _Float16* ybL = yL + (size_t)bl * gN * CIO;
  int mt_base = mb * (M_BLK / 32) + (w >> 1) * MF;

  for (int kt = 0; kt < KT; ++kt) {
    __syncthreads();
    // stage B tile: rows [n0-48, n0+176), 32 ci, hi+lo planes
#pragma unroll
    for (int it = 0; it < 7; ++it) {
      int task = it * 256 + tid;       // < 1792 = 224*2*4
      int row = task >> 3;
      int pl = (task >> 2) & 1, seg = task & 3;
      int n = n0 - 48 + row;
      uint4 vv = make_uint4(0u, 0u, 0u, 0u);
      if (n >= 0 && n < gN)
        vv = *(const uint4*)((pl ? ybL : ybH) + (size_t)n * CIO + kt * 32 + seg * 8);
      *(uint4*)((pl ? BL : BH) + row * KP + seg * 8) = vv;
    }
    __syncthreads();
#pragma unroll
    for (int dt = 0; dt < 5; ++dt) {
      int rowb = (w & 1) * 64 + dt * 24 + (lane & 31);
#pragma unroll
      for (int ks = 0; ks < 2; ++ks) {
        int koff = ks * 16 + ((lane >> 5) << 3);
        half8 bh0 = *(const half8*)(BH + rowb * KP + koff);
        half8 bh1 = *(const half8*)(BH + (rowb + 32) * KP + koff);
        half8 bl0 = *(const half8*)(BL + rowb * KP + koff);
        half8 bl1 = *(const half8*)(BL + (rowb + 32) * KP + koff);
#pragma unroll
        for (int mf = 0; mf < MF; ++mf) {
          int fid = ((((mt_base + mf) * KT + kt) * 2 + ks) * 5 + dt) * 2;
          half8 ah = *(const half8*)(Apack + ((size_t)fid * 64 + lane) * 8);
          half8 al = *(const half8*)(Apack + ((size_t)(fid + 1) * 64 + lane) * 8);
          acc[mf][0] = __builtin_amdgcn_mfma_f32_32x32x16_f16(ah, bh0, acc[mf][0], 0, 0, 0);
          acc[mf][1] = __builtin_amdgcn_mfma_f32_32x32x16_f16(ah, bh1, acc[mf][1], 0, 0, 0);
          acc[mf][0] = __builtin_amdgcn_mfma_f32_32x32x16_f16(ah, bl0, acc[mf][0], 0, 0, 0);
          acc[mf][1] = __builtin_amdgcn_mfma_f32_32x32x16_f16(ah, bl1, acc[mf][1], 0, 0, 0);
          acc[mf][0] = __builtin_amdgcn_mfma_f32_32x32x16_f16(al, bh0, acc[mf][0], 0, 0, 0);
          acc[mf][1] = __builtin_amdgcn_mfma_f32_32x32x16_f16(al, bh1, acc[mf][1], 0, 0, 0);
        }
      }
    }
  }

  // epilogue: bias + bn2 (+res) + relu -> h[t][co][v] fp32
  const float* rbase = res ? res + (size_t)bl * gN * CIO : nullptr;
  float* hbase = h_out + (size_t)bl * gN * CIO;
#pragma unroll
  for (int mf = 0; mf < MF; ++mf) {
    int m32 = mb * M_BLK + (w >> 1) * MF * 32 + mf * 32 + 4 * (lane >> 5);
#pragma unroll
    for (int nf = 0; nf < 2; ++nf) {
      int n = n0 + (w & 1) * 64 + nf * 32 + (lane & 31);
      int t = (int)(((unsigned)n * 43691u) >> 20);
      int v = n - t * 24;
      size_t nb_off = (size_t)t * CIO * 24 + v;
#pragma unroll
      for (int r = 0; r < 16; ++r) {
        int co = m32 + (r & 3) + 8 * (r >> 2);
        float z = (acc[mf][nf][r] + tbL[co]) * scL[co] + ofL[co];
        if (rbase) z += rbase[nb_off + (size_t)co * 24];
        hbase[nb_off + (size_t)co * 24] = fmaxf(z, 0.f);
      }
    }
  }
}

// ============================= final FC =============================
__global__ __launch_bounds__(256) void k_fcn(
    const float* __restrict__ h,   // [Bc][T][64][24]
    const float* __restrict__ fw,  // [6][64]
    const float* __restrict__ fb,  // [6]
    float* __restrict__ out,       // [B][T][24][6]
    int b0)
{
  __shared__ float hLf[64 * 24];
  __shared__ float fwL[384];
  int t = blockIdx.x, bl = blockIdx.y, tid = threadIdx.x;
  int b = b0 + bl;
  const float* hb = h + ((size_t)bl * gT + t) * 64 * 24;
  for (int i = tid; i < 64 * 24 / 4; i += 256) ((float4*)hLf)[i] = ((const float4*)hb)[i];
  for (int i = tid; i < 384; i += 256) fwL[i] = fw[i];
  __syncthreads();
  if (tid < 144) {
    int v = tid / 6, o = tid % 6;
    float acc = fb[o];
#pragma unroll 8
    for (int cc = 0; cc < 64; ++cc) acc += hLf[cc * 24 + v] * fwL[o * 64 + cc];
    out[(((size_t)b * gT + t) * gV + v) * 6 + o] = acc;
  }
}

// ============================= host =============================
extern "C" void kernel_launch(void* const* d_in, const int* in_sizes, int n_in,
                              void* d_out, int out_size, void* d_ws, size_t ws_size,
                              hipStream_t stream) {
  const float* x    = (const float*)d_in[0];
  const float* A    = (const float*)d_in[1];
  const float* dbg  = (const float*)d_in[2];
  const float* dbb  = (const float*)d_in[3];
  const float* ei0  = (const float*)d_in[4];
  const float* ei1  = (const float*)d_in[5];
  const float* ei2  = (const float*)d_in[6];
  const float* w0g  = (const float*)d_in[7];
  const float* gb0  = (const float*)d_in[8];
  const float* g10  = (const float*)d_in[9];
  const float* b10  = (const float*)d_in[10];
  const float* tw0  = (const float*)d_in[11];
  const float* tb0  = (const float*)d_in[12];
  const float* g20  = (const float*)d_in[13];
  const float* b20  = (const float*)d_in[14];
  const float* w1g  = (const float*)d_in[15];
  const float* gb1  = (const float*)d_in[16];
  const float* g11  = (const float*)d_in[17];
  const float* b11  = (const float*)d_in[18];
  const float* tw1  = (const float*)d_in[19];
  const float* tb1  = (const float*)d_in[20];
  const float* g21  = (const float*)d_in[21];
  const float* b21  = (const float*)d_in[22];
  const float* rw1  = (const float*)d_in[23];
  const float* rb1  = (const float*)d_in[24];
  const float* rg1  = (const float*)d_in[25];
  const float* rbb1 = (const float*)d_in[26];
  const float* w2g  = (const float*)d_in[27];
  const float* gb2  = (const float*)d_in[28];
  const float* g12  = (const float*)d_in[29];
  const float* b12  = (const float*)d_in[30];
  const float* tw2  = (const float*)d_in[31];
  const float* tb2  = (const float*)d_in[32];
  const float* g22  = (const float*)d_in[33];
  const float* b22  = (const float*)d_in[34];
  const float* rw2  = (const float*)d_in[35];
  const float* rb2  = (const float*)d_in[36];
  const float* rg2  = (const float*)d_in[37];
  const float* rbb2 = (const float*)d_in[38];
  const float* fw   = (const float*)d_in[39];
  const float* fb   = (const float*)d_in[40];
  float* outp = (float*)d_out;
  float* ws = (float*)d_ws;

  // ws layout (floats)
  size_t off = 0;
  auto alloc = [&](size_t n) { size_t o = off; off += n; return o; };
  size_t oAE = alloc(3 * 1728);
  size_t oCS = alloc(3 * 72);
  size_t oW1 = alloc((size_t)3 * 256 * 128);
  size_t oW2 = alloc((size_t)3 * 128 * 64);
  size_t oR1 = alloc((size_t)256 * 128);
  size_t oR2 = alloc((size_t)128 * 64);
  // packed tcn weight fragments (halves; sized in floats = halves/2)
  size_t oA0 = alloc((size_t)1280 * 512 / 2);
  size_t oA1 = alloc((size_t)320 * 512 / 2);
  size_t oA2 = alloc((size_t)80 * 512 / 2);
  off = (off + 3) & ~(size_t)3;

  // per-batch regions: yHL (hi+lo halves = perBf floats), h (perBf floats), r (perBf/2)
  const size_t perBf = (size_t)gN * 256;              // 1,572,864
  const size_t bytesPerBatch = perBf * 2 * 2 + perBf * 4 + perBf * 2; // 15,728,640
  int Bc = 32;
  while (Bc > 1 && (off * 4 + (size_t)Bc * bytesPerBatch) > ws_size) Bc >>= 1;

  float* regY = ws + off;                      // yH | yL halves
  float* regH = regY + perBf * Bc;             // fp32 h
  float* regR = regH + perBf * Bc;             // fp32 r (<=128ch)
  _Float16* yHp = (_Float16*)regY;
  _Float16* yLp = yHp + perBf * Bc;
  _Float16* A0 = (_Float16*)(ws + oA0);
  _Float16* A1 = (_Float16*)(ws + oA1);
  _Float16* A2 = (_Float16*)(ws + oA2);

  // ---- prep ----
  k_prep_aeff<<<21, 256, 0, stream>>>(A, ei0, ei1, ei2, ws + oAE, ws + oCS);
  auto tgrid = [](int n) { return dim3((n + 255) / 256); };
  k_transpose<<<tgrid(3 * 256 * 128), 256, 0, stream>>>(w1g, ws + oW1, 3, 256, 128);
  k_transpose<<<tgrid(3 * 128 * 64), 256, 0, stream>>>(w2g, ws + oW2, 3, 128, 64);
  k_transpose<<<tgrid(256 * 128), 256, 0, stream>>>(rw1, ws + oR1, 1, 256, 128);
  k_transpose<<<tgrid(128 * 64), 256, 0, stream>>>(rw2, ws + oR2, 1, 128, 64);
  k_prep_twf<<<320, 256, 0, stream>>>(tw0, A0, 256, 8);
  k_prep_twf<<<80, 256, 0, stream>>>(tw1, A1, 128, 4);
  k_prep_twf<<<20, 256, 0, stream>>>(tw2, A2, 64, 2);

  for (int b0 = 0; b0 < 32; b0 += Bc) {
    dim3 gbt(gT, Bc);
    // layer 0
    k_gcn0<<<gbt, 256, 0, stream>>>(x, ws + oAE, ws + oCS, dbg, dbb, w0g, gb0, g10, b10,
                                    yHp, yLp, b0);
    k_tcn_mfma<256, 2><<<dim3(48, 2, Bc), 256, 0, stream>>>(yHp, yLp, A0, tb0, g20, b20,
                                                            nullptr, regH);
    // layer 1
    k_gcn12<256, 128><<<gbt, 256, 0, stream>>>(regH, ws + oAE + 1728, ws + oCS + 72, ws + oW1,
                                               gb1, g11, b11, ws + oR1, rb1, rg1, rbb1,
                                               yHp, yLp, regR);
    k_tcn_mfma<128, 2><<<dim3(48, 1, Bc), 256, 0, stream>>>(yHp, yLp, A1, tb1, g21, b21,
                                                            regR, regH);
    // layer 2
    k_gcn12<128, 64><<<gbt, 256, 0, stream>>>(regH, ws + oAE + 2 * 1728, ws + oCS + 144, ws + oW2,
                                              gb2, g12, b12, ws + oR2, rb2, rg2, rbb2,
                                              yHp, yLp, regR);
    k_tcn_mfma<64, 1><<<dim3(48, 1, Bc), 256, 0, stream>>>(yHp, yLp, A2, tb2, g22, b22,
                                                           regR, regH);
    // final FC
    k_fcn<<<gbt, 256, 0, stream>>>(regH, fw, fb, outp, b0);
  }
  (void)in_sizes; (void)n_in; (void)out_size;
}

// Round 8
// 2056.651 us; speedup vs baseline: 2.0434x; 1.1841x over previous
//
#include <hip/hip_runtime.h>

typedef _Float16 half8 __attribute__((ext_vector_type(8)));
typedef _Float16 half2v __attribute__((ext_vector_type(2)));
typedef float floatx16 __attribute__((ext_vector_type(16)));

static constexpr int gT = 256;      // time steps
static constexpr int gV = 24;       // graph nodes
static constexpr int gN = gT * gV;  // 6144 columns per batch
static constexpr float BN_INV = 0.99999500003749969f; // 1/sqrt(1+1e-5)

// ============================= prep kernels =============================
__global__ __launch_bounds__(256) void k_prep_aeff(
    const float* __restrict__ A, const float* __restrict__ e0,
    const float* __restrict__ e1, const float* __restrict__ e2,
    float* __restrict__ aeff, float* __restrict__ csum)
{
  int tid = blockIdx.x * 256 + threadIdx.x;
  if (tid < 3 * 1728) {
    int l = tid / 1728, r = tid % 1728;
    const float* e = (l == 0) ? e0 : ((l == 1) ? e1 : e2);
    aeff[tid] = A[r] * e[r];
  }
  if (tid < 3 * 72) {
    int l = tid / 72, r = tid % 72;
    int k = r / 24, w = r % 24;
    const float* e = (l == 0) ? e0 : ((l == 1) ? e1 : e2);
    float s = 0.f;
    for (int v = 0; v < 24; ++v) { int idx = (k * 24 + v) * 24 + w; s += A[idx] * e[idx]; }
    csum[tid] = s;
  }
}

// Pack tcn weights into MFMA A-fragment order, f16 hi/lo split.
// frag id = ((((mt*KT + kt)*2 + ks)*5 + dt)*2 + pl); lane l: m = mt*32+(l&31),
// k(ci) = kt*32 + ks*16 + (l>>5)*8 + e  (v_mfma_f32_32x32x16_f16 A layout).
__global__ __launch_bounds__(256) void k_prep_twf(
    const float* __restrict__ tw, _Float16* __restrict__ out, int CI, int KT)
{
  int g = blockIdx.x * 256 + threadIdx.x;
  int fid = g >> 6, lane = g & 63;
  int pl = fid & 1;
  int f2 = fid >> 1;
  int dt = f2 % 5;
  int f3 = f2 / 5;
  int ks = f3 & 1;
  int f4 = f3 >> 1;
  int kt = f4 % KT;
  int mt = f4 / KT;
  int m = mt * 32 + (lane & 31);
  int kb = kt * 32 + ks * 16 + ((lane >> 5) << 3);
  half8 o;
#pragma unroll
  for (int e = 0; e < 8; ++e) {
    float v = tw[((size_t)m * CI + (kb + e)) * 5 + dt];
    _Float16 h = (_Float16)v;
    o[e] = pl ? (_Float16)(v - (float)h) : h;
  }
  *(half8*)(out + ((size_t)fid * 64 + lane) * 8) = o;
}

// Pack gcn W_big = [Wg(3*COUT rows); Wr(COUT rows)] into zgemm A-fragments.
// frag id = (((mt*KT + kt)*2 + ks)*2 + pl); same lane layout as k_prep_twf.
__global__ __launch_bounds__(256) void k_pack_wz(
    const float* __restrict__ Wg, const float* __restrict__ Wr,
    _Float16* __restrict__ out, int CIN, int KT, int M3)
{
  int g = blockIdx.x * 256 + threadIdx.x;
  int fid = g >> 6, lane = g & 63;
  int pl = fid & 1;
  int ks = (fid >> 1) & 1;
  int rest = fid >> 2;
  int kt = rest % KT;
  int mt = rest / KT;
  int m = mt * 32 + (lane & 31);
  int kb = kt * 32 + ks * 16 + ((lane >> 5) << 3);
  const float* row = (m < M3) ? (Wg + (size_t)m * CIN) : (Wr + (size_t)(m - M3) * CIN);
  half8 o;
#pragma unroll
  for (int e = 0; e < 8; ++e) {
    float v = row[kb + e];
    _Float16 h = (_Float16)v;
    o[e] = pl ? (_Float16)(v - (float)h) : h;
  }
  *(half8*)(out + ((size_t)fid * 64 + lane) * 8) = o;
}

// ============================= layer 0 GCN =============================
// fused data_bn + gcn(3->256) + bn1 + relu; emits f16 hi/lo planes [n][256]
__global__ __launch_bounds__(256) void k_gcn0(
    const float* __restrict__ x,      // [B][T][24][3]
    const float* __restrict__ aeff,   // [3][24][24]
    const float* __restrict__ csum,   // [3][24]
    const float* __restrict__ dbg, const float* __restrict__ dbb,  // [72]
    const float* __restrict__ W0,     // [768][3]
    const float* __restrict__ gb0,    // [768]
    const float* __restrict__ g1, const float* __restrict__ b1,    // [256]
    _Float16* __restrict__ yh, _Float16* __restrict__ yl,          // [NBc][256]
    int b0)
{
  __shared__ float xbn[72];      // [cin][v]
  __shared__ float XA[216];      // [(k*3+ci)][w]
  __shared__ float WL[2304];
  __shared__ float tile[256 * 25];
  int t = blockIdx.x, bl = blockIdx.y, tid = threadIdx.x;
  int b = b0 + bl;

  if (tid < 72) {
    int v = tid / 3, cin = tid % 3;
    float xv = x[(((size_t)b * gT + t) * gV + v) * 3 + cin];
    xbn[cin * 24 + v] = xv * (BN_INV * dbg[tid]) + dbb[tid];
  }
  for (int i = tid; i < 2304; i += 256) WL[i] = W0[i];
  __syncthreads();

  if (tid < 216) {
    int k = tid / 72, r = tid % 72, ci = r / 24, w = r % 24;
    const float* Ak = aeff + k * 576;
    float s = 0.f;
#pragma unroll
    for (int v = 0; v < 24; ++v) s += xbn[ci * 24 + v] * Ak[v * 24 + w];
    XA[tid] = s;
  }
  __syncthreads();

  int c = tid;
  float acc[24];
#pragma unroll
  for (int w = 0; w < 24; ++w) acc[w] = 0.f;
#pragma unroll
  for (int k = 0; k < 3; ++k) {
#pragma unroll
    for (int ci = 0; ci < 3; ++ci) {
      float wv = WL[(k * 256 + c) * 3 + ci];
#pragma unroll
      for (int w = 0; w < 24; ++w) acc[w] += wv * XA[(k * 3 + ci) * 24 + w];
    }
    float gv = gb0[k * 256 + c];
#pragma unroll
    for (int w = 0; w < 24; ++w) acc[w] += gv * csum[k * 24 + w];
  }
  float s1 = BN_INV * g1[c], o1 = b1[c];
#pragma unroll
  for (int w = 0; w < 24; ++w) tile[c * 25 + w] = fmaxf(acc[w] * s1 + o1, 0.f);
  __syncthreads();

  size_t nb = ((size_t)bl * gN + (size_t)t * 24);
#pragma unroll
  for (int it = 0; it < 12; ++it) {
    int idx = it * 256 + tid;          // < 3072
    int w = idx >> 7;
    int c0 = (idx & 127) * 2;
    float v0 = tile[c0 * 25 + w], v1 = tile[(c0 + 1) * 25 + w];
    _Float16 h0 = (_Float16)v0, h1 = (_Float16)v1;
    _Float16 l0 = (_Float16)(v0 - (float)h0), l1 = (_Float16)(v1 - (float)h1);
    size_t a = (nb + w) * 256 + c0;
    half2v ph; ph[0] = h0; ph[1] = h1;
    half2v plv; plv[0] = l0; plv[1] = l1;
    *(half2v*)(yh + a) = ph;
    *(half2v*)(yl + a) = plv;
  }
}

// ============================= gcn Z-GEMM (MFMA) =============================
// Z[m][n] = sum_ci Wbig[m][ci] * h[ci][n], hi/lo split (3 MFMA per product).
// M block = 128 per grid.y; N block = 128; K template.
template <int K>
__global__ __launch_bounds__(256) void k_zgemm(
    const _Float16* __restrict__ pH, const _Float16* __restrict__ pL, // [N][K]
    const _Float16* __restrict__ Wf, float* __restrict__ Z, int NBc)
{
  constexpr int KT = K / 32;
  __shared__ _Float16 BH[128 * 40];
  __shared__ _Float16 BL[128 * 40];
  int bx = blockIdx.x, mb = blockIdx.y;
  int tid = threadIdx.x, w = tid >> 6, lane = tid & 63;
  int n0 = bx * 128;
  int mt_base = mb * 4 + (w >> 1) * 2;
  floatx16 acc[2][2] = {};

  for (int kt = 0; kt < KT; ++kt) {
    __syncthreads();
#pragma unroll
    for (int it = 0; it < 4; ++it) {
      int task = it * 256 + tid;       // 1024 = 128 rows * 2 planes * 4 segs
      int row = task >> 3, pl = (task >> 2) & 1, seg = task & 3;
      uint4 vv = *(const uint4*)((pl ? pL : pH) + (size_t)(n0 + row) * K + kt * 32 + seg * 8);
      *(uint4*)((pl ? BL : BH) + row * 40 + seg * 8) = vv;
    }
    __syncthreads();
#pragma unroll
    for (int ks = 0; ks < 2; ++ks) {
      int koff = ks * 16 + ((lane >> 5) << 3);
      int rowb = (w & 1) * 64 + (lane & 31);
      half8 bh0 = *(const half8*)(BH + rowb * 40 + koff);
      half8 bh1 = *(const half8*)(BH + (rowb + 32) * 40 + koff);
      half8 bl0 = *(const half8*)(BL + rowb * 40 + koff);
      half8 bl1 = *(const half8*)(BL + (rowb + 32) * 40 + koff);
#pragma unroll
      for (int mf = 0; mf < 2; ++mf) {
        int fid = (((mt_base + mf) * KT + kt) * 2 + ks) * 2;
        half8 ah = *(const half8*)(Wf + ((size_t)fid * 64 + lane) * 8);
        half8 al = *(const half8*)(Wf + ((size_t)(fid + 1) * 64 + lane) * 8);
        acc[mf][0] = __builtin_amdgcn_mfma_f32_32x32x16_f16(ah, bh0, acc[mf][0], 0, 0, 0);
        acc[mf][1] = __builtin_amdgcn_mfma_f32_32x32x16_f16(ah, bh1, acc[mf][1], 0, 0, 0);
        acc[mf][0] = __builtin_amdgcn_mfma_f32_32x32x16_f16(ah, bl0, acc[mf][0], 0, 0, 0);
        acc[mf][1] = __builtin_amdgcn_mfma_f32_32x32x16_f16(ah, bl1, acc[mf][1], 0, 0, 0);
        acc[mf][0] = __builtin_amdgcn_mfma_f32_32x32x16_f16(al, bh0, acc[mf][0], 0, 0, 0);
        acc[mf][1] = __builtin_amdgcn_mfma_f32_32x32x16_f16(al, bh1, acc[mf][1], 0, 0, 0);
      }
    }
  }
  // store Z[m][n] (coalesced dwords: 32 lanes consecutive n)
#pragma unroll
  for (int mf = 0; mf < 2; ++mf) {
    int mbase = mb * 128 + ((w >> 1) * 2 + mf) * 32 + 4 * (lane >> 5);
#pragma unroll
    for (int nf = 0; nf < 2; ++nf) {
      int n = n0 + (w & 1) * 64 + nf * 32 + (lane & 31);
#pragma unroll
      for (int r = 0; r < 16; ++r) {
        int m = mbase + (r & 3) + 8 * (r >> 2);
        Z[(size_t)m * NBc + n] = acc[mf][nf][r];
      }
    }
  }
}

// ============================= A-contraction =============================
// y[c][w] = relu(bn1( sum_{k,v} Z[k*COUT+c][v]*Aeff[k,v,w] + sum_k gb[k*COUT+c]*csum[k,w] ))
// emits hi/lo planes [n][COUT].  (res rows of Z are consumed by k_tcn_mfma directly.)
template <int COUT>
__global__ __launch_bounds__(256) void k_acontract(
    const float* __restrict__ Z, const float* __restrict__ aeffL,
    const float* __restrict__ csumL, const float* __restrict__ gb,
    const float* __restrict__ g1, const float* __restrict__ b1,
    _Float16* __restrict__ oH, _Float16* __restrict__ oL, int NBc)
{
  constexpr int M3 = 3 * COUT;
  constexpr int SUBS = 256 / COUT;
  constexpr int WR = 24 / SUBS;
  __shared__ float ZL[M3 * 25];
  __shared__ float AL[3 * 576];
  __shared__ float csL[72];
  int t = blockIdx.x, bl = blockIdx.y, tid = threadIdx.x;
  size_t nb = (size_t)bl * gN + (size_t)t * 24;

  for (int i = tid; i < 1728; i += 256) AL[i] = aeffL[i];
  if (tid < 72) csL[tid] = csumL[tid];
  for (int i = tid; i < M3 * 24; i += 256) {
    int row = i / 24, v = i % 24;
    ZL[row * 25 + v] = Z[(size_t)row * NBc + nb + v];
  }
  __syncthreads();

  int c = tid & (COUT - 1);
  int sub = tid / COUT;
  int w0 = sub * WR;

  float z[3][24];
#pragma unroll
  for (int k = 0; k < 3; ++k)
#pragma unroll
    for (int v = 0; v < 24; ++v) z[k][v] = ZL[(k * COUT + c) * 25 + v];

  float y[WR];
#pragma unroll
  for (int j = 0; j < WR; ++j) y[j] = 0.f;
#pragma unroll
  for (int k = 0; k < 3; ++k)
#pragma unroll
    for (int v = 0; v < 24; ++v) {
      float zr = z[k][v];
      const float* ap = &AL[k * 576 + v * 24 + w0];
#pragma unroll
      for (int j = 0; j < WR; ++j) y[j] += zr * ap[j];
    }

  float s1 = BN_INV * g1[c], o1 = b1[c];
  float gv0 = gb[c], gv1 = gb[COUT + c], gv2 = gb[2 * COUT + c];
  __syncthreads();                      // about to reuse ZL as staging
  constexpr int PITCH = COUT / 2 + 1;   // dwords
  _Float16* YH16 = (_Float16*)ZL;       // hi rows [0,24), lo rows [24,48)
#pragma unroll
  for (int j = 0; j < WR; ++j) {
    int w = w0 + j;
    float bias = gv0 * csL[w] + gv1 * csL[24 + w] + gv2 * csL[48 + w];
    float yv = fmaxf((y[j] + bias) * s1 + o1, 0.f);
    _Float16 h = (_Float16)yv;
    _Float16 lo = (_Float16)(yv - (float)h);
    YH16[w * PITCH * 2 + c] = h;
    YH16[(24 + w) * PITCH * 2 + c] = lo;
  }
  __syncthreads();
  constexpr int CP2 = COUT / 2;
  uint* YST = (uint*)ZL;
  uint* oH32 = (uint*)oH;
  uint* oL32 = (uint*)oL;
#pragma unroll
  for (int i = 0; i < 24 * CP2 / 256; ++i) {
    int idx = i * 256 + tid;
    int row = idx / CP2, col = idx % CP2;
    oH32[(nb + row) * CP2 + col] = YST[row * PITCH + col];
    oL32[(nb + row) * CP2 + col] = YST[(24 + row) * PITCH + col];
  }
}

// ============================= temporal conv (MFMA) =============================
// C[co, n] = sum_dt A_dt[co,ci] @ B[ci, n+(dt-2)*24]; + tb, bn2, (+bn(res) from Z), relu.
// Emits hi/lo planes [n][CIO] via LDS-transposed coalesced writes.
template <int CIO, int MF>
__global__ __launch_bounds__(256) void k_tcn_mfma(
    const _Float16* __restrict__ yH, const _Float16* __restrict__ yL, // [NBc][CIO]
    const _Float16* __restrict__ Apack,
    const float* __restrict__ tb, const float* __restrict__ g2, const float* __restrict__ b2,
    const float* __restrict__ Zres,   // pre-offset to res rows of Z: [CIO][NBc], or nullptr
    const float* __restrict__ rb, const float* __restrict__ rg, const float* __restrict__ rbb,
    _Float16* __restrict__ oH, _Float16* __restrict__ oL,  // [NBc][CIO]
    int NBc)
{
  constexpr int KT = CIO / 32;
  constexpr int M_BLK = MF * 64;
  constexpr int NROW = 224, KP = 40;
  __shared__ uint SMEMu[8960];                 // BH|BL staging, reused as ST
  _Float16* BH = (_Float16*)SMEMu;             // [224*40]
  _Float16* BL = BH + NROW * KP;               // [224*40]
  __shared__ float scL[CIO], ofL[CIO], tbL[CIO], rscL[CIO], rofL[CIO], rbvL[CIO];
  int bx = blockIdx.x, mb = blockIdx.y, bl = blockIdx.z;
  int tid = threadIdx.x, w = tid >> 6, lane = tid & 63;
  int n0 = bx * 128;

  for (int i = tid; i < CIO; i += 256) {
    scL[i] = BN_INV * g2[i]; ofL[i] = b2[i]; tbL[i] = tb[i];
    if (Zres) { rscL[i] = BN_INV * rg[i]; rofL[i] = rbb[i]; rbvL[i] = rb[i]; }
  }

  floatx16 acc[MF][2] = {};
  const _Float16* ybH = yH + (size_t)bl * gN * CIO;
  const _Float16* ybL = yL + (size_t)bl * gN * CIO;
  int mt_base = mb * (M_BLK / 32) + (w >> 1) * MF;

  for (int kt = 0; kt < KT; ++kt) {
    __syncthreads();
#pragma unroll
    for (int it = 0; it < 7; ++it) {
      int task = it * 256 + tid;       // < 1792 = 224 rows * 2 planes * 4 segs
      int row = task >> 3;
      int pl = (task >> 2) & 1, seg = task & 3;
      int n = n0 - 48 + row;
      uint4 vv = make_uint4(0u, 0u, 0u, 0u);
      if (n >= 0 && n < gN)
        vv = *(const uint4*)((pl ? ybL : ybH) + (size_t)n * CIO + kt * 32 + seg * 8);
      *(uint4*)((pl ? BL : BH) + row * KP + seg * 8) = vv;
    }
    __syncthreads();
#pragma unroll
    for (int dt = 0; dt < 5; ++dt) {
      int rowb = (w & 1) * 64 + dt * 24 + (lane & 31);
#pragma unroll
      for (int ks = 0; ks < 2; ++ks) {
        int koff = ks * 16 + ((lane >> 5) << 3);
        half8 bh0 = *(const half8*)(BH + rowb * KP + koff);
        half8 bh1 = *(const half8*)(BH + (rowb + 32) * KP + koff);
        half8 bl0 = *(const half8*)(BL + rowb * KP + koff);
        half8 bl1 = *(const half8*)(BL + (rowb + 32) * KP + koff);
#pragma unroll
        for (int mf = 0; mf < MF; ++mf) {
          int fid = ((((mt_base + mf) * KT + kt) * 2 + ks) * 5 + dt) * 2;
          half8 ah = *(const half8*)(Apack + ((size_t)fid * 64 + lane) * 8);
          half8 al = *(const half8*)(Apack + ((size_t)(fid + 1) * 64 + lane) * 8);
          acc[mf][0] = __builtin_amdgcn_mfma_f32_32x32x16_f16(ah, bh0, acc[mf][0], 0, 0, 0);
          acc[mf][1] = __builtin_amdgcn_mfma_f32_32x32x16_f16(ah, bh1, acc[mf][1], 0, 0, 0);
          acc[mf][0] = __builtin_amdgcn_mfma_f32_32x32x16_f16(ah, bl0, acc[mf][0], 0, 0, 0);
          acc[mf][1] = __builtin_amdgcn_mfma_f32_32x32x16_f16(ah, bl1, acc[mf][1], 0, 0, 0);
          acc[mf][0] = __builtin_amdgcn_mfma_f32_32x32x16_f16(al, bh0, acc[mf][0], 0, 0, 0);
          acc[mf][1] = __builtin_amdgcn_mfma_f32_32x32x16_f16(al, bh1, acc[mf][1], 0, 0, 0);
        }
      }
    }
  }

  // epilogue: acc -> z (bias + bn2 + res + relu), in place
  int blgN = bl * gN;
#pragma unroll
  for (int mf = 0; mf < MF; ++mf) {
    int m32 = mb * M_BLK + (w >> 1) * MF * 32 + mf * 32 + 4 * (lane >> 5);
#pragma unroll
    for (int nf = 0; nf < 2; ++nf) {
      int n = n0 + (w & 1) * 64 + nf * 32 + (lane & 31);
      size_t nflat = (size_t)blgN + n;
#pragma unroll
      for (int r = 0; r < 16; ++r) {
        int co = m32 + (r & 3) + 8 * (r >> 2);
        float z = (acc[mf][nf][r] + tbL[co]) * scL[co] + ofL[co];
        if (Zres) z += (Zres[(size_t)co * NBc + nflat] + rbvL[co]) * rscL[co] + rofL[co];
        acc[mf][nf][r] = fmaxf(z, 0.f);
      }
    }
  }

  // LDS-transpose + coalesced plane writes (two passes: hi, lo)
  constexpr int CPB = M_BLK / 2;     // co-pairs per block
  constexpr int PITCH = CPB + 1;     // dwords
  uint* ST = SMEMu;
  int cob2 = (mb * M_BLK) >> 1;
  uint* oH32 = (uint*)oH;
  uint* oL32 = (uint*)oL;
  constexpr int ITERS = 128 * CPB / 256;

#pragma unroll
  for (int pass = 0; pass < 2; ++pass) {
    __syncthreads();
#pragma unroll
    for (int mf = 0; mf < MF; ++mf) {
      int cl = (w >> 1) * MF * 32 + mf * 32 + 4 * (lane >> 5);
#pragma unroll
      for (int nf = 0; nf < 2; ++nf) {
        int nl = (w & 1) * 64 + nf * 32 + (lane & 31);
#pragma unroll
        for (int r = 0; r < 16; r += 2) {
          float z0 = acc[mf][nf][r], z1 = acc[mf][nf][r + 1];
          _Float16 a0 = (_Float16)z0, a1 = (_Float16)z1;
          if (pass == 1) { a0 = (_Float16)(z0 - (float)a0); a1 = (_Float16)(z1 - (float)a1); }
          half2v p; p[0] = a0; p[1] = a1;
          int col2 = (cl + (r & 3) + 8 * (r >> 2)) >> 1;
          ST[nl * PITCH + col2] = *(uint*)&p;
        }
      }
    }
    __syncthreads();
    uint* dst = (pass == 0) ? oH32 : oL32;
#pragma unroll
    for (int i = 0; i < ITERS; ++i) {
      int idx = i * 256 + tid;
      int row = idx / CPB, col = idx % CPB;
      dst[((size_t)blgN + n0 + row) * (CIO / 2) + cob2 + col] = ST[row * PITCH + col];
    }
  }
}

// ============================= final FC =============================
__global__ __launch_bounds__(256) void k_fcn(
    const _Float16* __restrict__ pH, const _Float16* __restrict__ pL, // [NBc][64]
    const float* __restrict__ fw,  // [6][64]
    const float* __restrict__ fb,  // [6]
    float* __restrict__ out,       // [B][T][24][6]
    int b0)
{
  __shared__ float hLf[64 * 25];
  __shared__ float fwL[384];
  int t = blockIdx.x, bl = blockIdx.y, tid = threadIdx.x;
  int b = b0 + bl;
  size_t nb = (size_t)bl * gN + (size_t)t * 24;
  const uint* pH32 = (const uint*)pH;
  const uint* pL32 = (const uint*)pL;
#pragma unroll
  for (int i = 0; i < 3; ++i) {
    int idx = i * 256 + tid;          // < 768 = 24 rows * 32 pairs
    int w = idx >> 5, c2 = (idx & 31) * 2;
    uint dh = pH32[(nb + w) * 32 + (idx & 31)];
    uint dl = pL32[(nb + w) * 32 + (idx & 31)];
    half2v vh = *(half2v*)&dh, vl = *(half2v*)&dl;
    hLf[c2 * 25 + w] = (float)vh[0] + (float)vl[0];
    hLf[(c2 + 1) * 25 + w] = (float)vh[1] + (float)vl[1];
  }
  for (int i = tid; i < 384; i += 256) fwL[i] = fw[i];
  __syncthreads();
  if (tid < 144) {
    int v = tid / 6, o = tid % 6;
    float acc = fb[o];
#pragma unroll 8
    for (int cc = 0; cc < 64; ++cc) acc += hLf[cc * 25 + v] * fwL[o * 64 + cc];
    out[(((size_t)b * gT + t) * gV + v) * 6 + o] = acc;
  }
}

// ============================= host =============================
extern "C" void kernel_launch(void* const* d_in, const int* in_sizes, int n_in,
                              void* d_out, int out_size, void* d_ws, size_t ws_size,
                              hipStream_t stream) {
  const float* x    = (const float*)d_in[0];
  const float* A    = (const float*)d_in[1];
  const float* dbg  = (const float*)d_in[2];
  const float* dbb  = (const float*)d_in[3];
  const float* ei0  = (const float*)d_in[4];
  const float* ei1  = (const float*)d_in[5];
  const float* ei2  = (const float*)d_in[6];
  const float* w0g  = (const float*)d_in[7];
  const float* gb0  = (const float*)d_in[8];
  const float* g10  = (const float*)d_in[9];
  const float* b10  = (const float*)d_in[10];
  const float* tw0  = (const float*)d_in[11];
  const float* tb0  = (const float*)d_in[12];
  const float* g20  = (const float*)d_in[13];
  const float* b20  = (const float*)d_in[14];
  const float* w1g  = (const float*)d_in[15];
  const float* gb1  = (const float*)d_in[16];
  const float* g11  = (const float*)d_in[17];
  const float* b11  = (const float*)d_in[18];
  const float* tw1  = (const float*)d_in[19];
  const float* tb1  = (const float*)d_in[20];
  const float* g21  = (const float*)d_in[21];
  const float* b21  = (const float*)d_in[22];
  const float* rw1  = (const float*)d_in[23];
  const float* rb1  = (const float*)d_in[24];
  const float* rg1  = (const float*)d_in[25];
  const float* rbb1 = (const float*)d_in[26];
  const float* w2g  = (const float*)d_in[27];
  const float* gb2  = (const float*)d_in[28];
  const float* g12  = (const float*)d_in[29];
  const float* b12  = (const float*)d_in[30];
  const float* tw2  = (const float*)d_in[31];
  const float* tb2  = (const float*)d_in[32];
  const float* g22  = (const float*)d_in[33];
  const float* b22  = (const float*)d_in[34];
  const float* rw2  = (const float*)d_in[35];
  const float* rb2  = (const float*)d_in[36];
  const float* rg2  = (const float*)d_in[37];
  const float* rbb2 = (const float*)d_in[38];
  const float* fw   = (const float*)d_in[39];
  const float* fb   = (const float*)d_in[40];
  float* outp = (float*)d_out;
  float* ws = (float*)d_ws;

  // ws layout (floats)
  size_t off = 0;
  auto alloc = [&](size_t n) { size_t o = off; off += n; return o; };
  size_t oAE  = alloc(3 * 1728);
  size_t oCS  = alloc(3 * 72);
  size_t oA0  = alloc((size_t)1280 * 512 / 2);  // tcn0 frags
  size_t oA1  = alloc((size_t)320 * 512 / 2);
  size_t oA2  = alloc((size_t)80 * 512 / 2);
  size_t oWz1 = alloc((size_t)512 * 512 / 2);   // 512 frags * 512 halves
  size_t oWz2 = alloc((size_t)128 * 512 / 2);
  off = (off + 3) & ~(size_t)3;

  // per batch: planes buf1 (n*256 fl) + planes buf2 (n*256 fl) + Z (512*n fl)
  const size_t perBatchBytes = (size_t)gN * 1024 * 4;   // 25.17 MB
  int Bc = 32;
  while (Bc > 1 && off * 4 + (size_t)Bc * perBatchBytes > ws_size) Bc >>= 1;
  int NBc = Bc * gN;

  float* B1 = ws + off;
  float* B2 = B1 + (size_t)NBc * 256;
  float* Zb = B2 + (size_t)NBc * 256;
  _Float16* b1h = (_Float16*)B1;
  _Float16* b2h = (_Float16*)B2;
  _Float16* A0 = (_Float16*)(ws + oA0);
  _Float16* A1 = (_Float16*)(ws + oA1);
  _Float16* A2 = (_Float16*)(ws + oA2);
  _Float16* Wz1 = (_Float16*)(ws + oWz1);
  _Float16* Wz2 = (_Float16*)(ws + oWz2);

  // ---- prep ----
  k_prep_aeff<<<21, 256, 0, stream>>>(A, ei0, ei1, ei2, ws + oAE, ws + oCS);
  k_prep_twf<<<320, 256, 0, stream>>>(tw0, A0, 256, 8);
  k_prep_twf<<<80, 256, 0, stream>>>(tw1, A1, 128, 4);
  k_prep_twf<<<20, 256, 0, stream>>>(tw2, A2, 64, 2);
  k_pack_wz<<<128, 256, 0, stream>>>(w1g, rw1, Wz1, 256, 8, 384);  // M=512,K=256
  k_pack_wz<<<32, 256, 0, stream>>>(w2g, rw2, Wz2, 128, 4, 192);   // M=256,K=128

  for (int b0 = 0; b0 < 32; b0 += Bc) {
    dim3 gbt(gT, Bc);
    // layer 0: gcn0 -> P1(256); tcn0 -> P2(256)
    k_gcn0<<<gbt, 256, 0, stream>>>(x, ws + oAE, ws + oCS, dbg, dbb, w0g, gb0, g10, b10,
                                    b1h, b1h + (size_t)NBc * 256, b0);
    k_tcn_mfma<256, 2><<<dim3(48, 2, Bc), 256, 0, stream>>>(
        b1h, b1h + (size_t)NBc * 256, A0, tb0, g20, b20,
        nullptr, nullptr, nullptr, nullptr,
        b2h, b2h + (size_t)NBc * 256, NBc);
    // layer 1: zgemm(P2->Z); acontract -> P1(128); tcn1(P1 + Zres) -> P2(128)
    k_zgemm<256><<<dim3(Bc * 48, 4, 1), 256, 0, stream>>>(
        b2h, b2h + (size_t)NBc * 256, Wz1, Zb, NBc);
    k_acontract<128><<<dim3(gT, Bc), 256, 0, stream>>>(
        Zb, ws + oAE + 1728, ws + oCS + 72, gb1, g11, b11,
        b1h, b1h + (size_t)NBc * 128, NBc);
    k_tcn_mfma<128, 2><<<dim3(48, 1, Bc), 256, 0, stream>>>(
        b1h, b1h + (size_t)NBc * 128, A1, tb1, g21, b21,
        Zb + (size_t)384 * NBc, rb1, rg1, rbb1,
        b2h, b2h + (size_t)NBc * 128, NBc);
    // layer 2
    k_zgemm<128><<<dim3(Bc * 48, 2, 1), 256, 0, stream>>>(
        b2h, b2h + (size_t)NBc * 128, Wz2, Zb, NBc);
    k_acontract<64><<<dim3(gT, Bc), 256, 0, stream>>>(
        Zb, ws + oAE + 2 * 1728, ws + oCS + 144, gb2, g12, b12,
        b1h, b1h + (size_t)NBc * 64, NBc);
    k_tcn_mfma<64, 1><<<dim3(48, 1, Bc), 256, 0, stream>>>(
        b1h, b1h + (size_t)NBc * 64, A2, tb2, g22, b22,
        Zb + (size_t)192 * NBc, rb2, rg2, rbb2,
        b2h, b2h + (size_t)NBc * 64, NBc);
    // final FC
    k_fcn<<<gbt, 256, 0, stream>>>(b2h, b2h + (size_t)NBc * 64, fw, fb, outp, b0);
  }
  (void)in_sizes; (void)n_in; (void)out_size;
}